// Round 1
// baseline (1577.604 us; speedup 1.0000x reference)
//
#include <hip/hip_runtime.h>

// ---- problem constants (from reference) ----
#define N_NODES   100000
#define T_TYPES   4
#define E_EDGES   400000
#define C_CH      2
#define L_LAYERS  2
#define W_INF     128
#define DD        64
#define NUM_CLASS 16
#define BETA      0.5f
#define M_TGT     10000

static const size_t CH_STRIDE = (size_t)N_NODES * DD;   // floats per channel plane

// ---------------------------------------------------------------------------
// filt[l][c][t] = softmax_t(conv_weights[l][c][t])   (L*C = 4 rows of T = 4)
// ---------------------------------------------------------------------------
__global__ void filt_kernel(const float* __restrict__ cw, float* __restrict__ filt) {
    int r = threadIdx.x;                 // row = l*C + c
    if (r < L_LAYERS * C_CH) {
        float v[T_TYPES];
        float m = -1e30f;
        #pragma unroll
        for (int t = 0; t < T_TYPES; ++t) { v[t] = cw[r * T_TYPES + t]; m = fmaxf(m, v[t]); }
        float s = 0.f;
        #pragma unroll
        for (int t = 0; t < T_TYPES; ++t) { v[t] = __expf(v[t] - m); s += v[t]; }
        #pragma unroll
        for (int t = 0; t < T_TYPES; ++t) filt[r * T_TYPES + t] = v[t] / s;
    }
}

// ---------------------------------------------------------------------------
// X_ [c][n][d] = sum_f X[n][f] * Ws[c][f][d]   (both channels fused)
// block = 256 threads, handles 16 rows; Ws (64KB) staged in LDS.
// lane = d -> LDS reads are stride-1 across 64 lanes (2-way, free);
// X reads are wave-broadcast (same address for all 64 lanes).
// ---------------------------------------------------------------------------
__global__ __launch_bounds__(256) void proj_kernel(const float* __restrict__ X,
                                                   const float* __restrict__ Ws,
                                                   float* __restrict__ Xp) {
    __shared__ float ws_lds[C_CH * W_INF * DD];   // 16384 floats = 64 KB
    int tid = threadIdx.x;
    {
        const float4* g = (const float4*)Ws;
        float4* s = (float4*)ws_lds;
        #pragma unroll
        for (int i = 0; i < 16; ++i) s[tid + 256 * i] = g[tid + 256 * i];
    }
    __syncthreads();

    int d  = tid & 63;
    int r0 = blockIdx.x * 16 + (tid >> 6);        // rows r0, r0+4, r0+8, r0+12
    const float* x0 = X + (size_t)r0 * W_INF;

    float acc0[4] = {0.f, 0.f, 0.f, 0.f};
    float acc1[4] = {0.f, 0.f, 0.f, 0.f};
    for (int f = 0; f < W_INF; ++f) {
        float w0 = ws_lds[f * DD + d];
        float w1 = ws_lds[W_INF * DD + f * DD + d];
        #pragma unroll
        for (int i = 0; i < 4; ++i) {
            float xv = x0[(size_t)(4 * i) * W_INF + f];
            acc0[i] = fmaf(xv, w0, acc0[i]);
            acc1[i] = fmaf(xv, w1, acc1[i]);
        }
    }
    #pragma unroll
    for (int i = 0; i < 4; ++i) {
        size_t o = (size_t)(r0 + 4 * i) * DD + d;
        Xp[o]             = acc0[i];
        Xp[CH_STRIDE + o] = acc1[i];
    }
}

// ---------------------------------------------------------------------------
// One layer of FastGTConv, both channels fused:
//   Hout[c][row[e]][d] += val[e] * filt[l][c][type(e)] * Hin[c][col[e]][d]
// 1 wave per edge (grid-stride), lane = d -> 256B coalesced gather + atomic.
// ---------------------------------------------------------------------------
__global__ __launch_bounds__(256) void spmm_kernel(const float* __restrict__ Hin,
                                                   float* __restrict__ Hout,
                                                   const int* __restrict__ edge_index,
                                                   const float* __restrict__ edge_value,
                                                   const float* __restrict__ filt,
                                                   int layer) {
    float fl[C_CH][T_TYPES];
    #pragma unroll
    for (int c = 0; c < C_CH; ++c)
        #pragma unroll
        for (int t = 0; t < T_TYPES; ++t)
            fl[c][t] = filt[layer * C_CH * T_TYPES + c * T_TYPES + t];

    int lane   = threadIdx.x & 63;
    int wave   = (blockIdx.x * blockDim.x + threadIdx.x) >> 6;
    int nwaves = (gridDim.x * blockDim.x) >> 6;

    for (int e = wave; e < T_TYPES * E_EDGES; e += nwaves) {
        int t  = e / E_EDGES;
        int ei = e - t * E_EDGES;
        int row = edge_index[(size_t)(t * 2) * E_EDGES + ei];
        int col = edge_index[(size_t)(t * 2 + 1) * E_EDGES + ei];
        float v  = edge_value[e];
        float w0 = v * fl[0][t];
        float w1 = v * fl[1][t];

        size_t ib = (size_t)col * DD + lane;
        size_t ob = (size_t)row * DD + lane;
        float x0 = Hin[ib];
        float x1 = Hin[CH_STRIDE + ib];
        unsafeAtomicAdd(&Hout[ob],             w0 * x0);
        unsafeAtomicAdd(&Hout[CH_STRIDE + ob], w1 * x1);
    }
}

// ---------------------------------------------------------------------------
// Tail, restricted to the M target rows:
//   hc[k]  = relu(beta*X_ + (1-beta)*H)         k = c*64+d  (128 values)
//   hmid[j]= hc . lin1_w[:,j] + lin1_b[j]       (64 values)
//   out[q] = hmid . lin_w[:,q] + lin_b[q]       (16 values)
// block = 256 = 4 waves, 1 wave per target; weights staged in LDS.
// ---------------------------------------------------------------------------
__global__ __launch_bounds__(256) void tail_kernel(const float* __restrict__ Xp,
                                                   const float* __restrict__ H,
                                                   const float* __restrict__ lin1_w,
                                                   const float* __restrict__ lin1_b,
                                                   const float* __restrict__ lin_w,
                                                   const float* __restrict__ lin_b,
                                                   const int* __restrict__ tgt,
                                                   float* __restrict__ out) {
    __shared__ float l1w[W_INF * DD];        // 32 KB
    __shared__ float lw[DD * NUM_CLASS];     // 4 KB
    __shared__ float l1b[DD];
    __shared__ float lb[NUM_CLASS];
    __shared__ float hc[4][W_INF];
    __shared__ float hmid[4][DD];

    int tid = threadIdx.x;
    {
        const float4* g = (const float4*)lin1_w;
        float4* s = (float4*)l1w;
        #pragma unroll
        for (int i = 0; i < 8; ++i) s[tid + 256 * i] = g[tid + 256 * i];
        ((float4*)lw)[tid] = ((const float4*)lin_w)[tid];   // 256 float4 exactly
        if (tid < DD) l1b[tid] = lin1_b[tid];
        else if (tid < DD + NUM_CLASS) lb[tid - DD] = lin_b[tid - DD];
    }
    __syncthreads();

    int w = tid >> 6, lane = tid & 63;
    int m = blockIdx.x * 4 + w;              // M = 10000 = 2500*4, always valid
    int n = tgt[m];
    size_t b0 = (size_t)n * DD + lane;
    float a = BETA * Xp[b0]             + (1.f - BETA) * H[b0];
    float b = BETA * Xp[CH_STRIDE + b0] + (1.f - BETA) * H[CH_STRIDE + b0];
    hc[w][lane]      = fmaxf(a, 0.f);
    hc[w][DD + lane] = fmaxf(b, 0.f);
    __syncthreads();

    float acc = l1b[lane];
    #pragma unroll 8
    for (int k = 0; k < W_INF; ++k)
        acc = fmaf(hc[w][k], l1w[k * DD + lane], acc);
    hmid[w][lane] = acc;
    __syncthreads();

    if (lane < NUM_CLASS) {
        float o = lb[lane];
        #pragma unroll 8
        for (int k = 0; k < DD; ++k)
            o = fmaf(hmid[w][k], lw[k * NUM_CLASS + lane], o);
        out[(size_t)m * NUM_CLASS + lane] = o;
    }
}

// ---------------------------------------------------------------------------
extern "C" void kernel_launch(void* const* d_in, const int* in_sizes, int n_in,
                              void* d_out, int out_size, void* d_ws, size_t ws_size,
                              hipStream_t stream) {
    const float* X            = (const float*)d_in[0];
    const float* edge_value   = (const float*)d_in[1];
    const float* conv_weights = (const float*)d_in[2];
    const float* Ws           = (const float*)d_in[3];
    const float* lin1_w       = (const float*)d_in[4];
    const float* lin1_b       = (const float*)d_in[5];
    const float* lin_w        = (const float*)d_in[6];
    const float* lin_b        = (const float*)d_in[7];
    const int*   edge_index   = (const int*)d_in[8];
    const int*   target_x     = (const int*)d_in[9];
    float* out = (float*)d_out;

    float* ws   = (float*)d_ws;
    float* Xp   = ws;                         // [C, N, D]
    float* B1   = ws + 2 * CH_STRIDE;         // [C, N, D]
    float* B2   = ws + 4 * CH_STRIDE;         // [C, N, D]
    float* filt = ws + 6 * CH_STRIDE;         // [L, C, T] = 16 floats

    hipMemsetAsync(B1, 0, 2 * CH_STRIDE * sizeof(float), stream);
    hipMemsetAsync(B2, 0, 2 * CH_STRIDE * sizeof(float), stream);

    filt_kernel<<<1, 64, 0, stream>>>(conv_weights, filt);
    proj_kernel<<<N_NODES / 16, 256, 0, stream>>>(X, Ws, Xp);
    spmm_kernel<<<4096, 256, 0, stream>>>(Xp, B1, edge_index, edge_value, filt, 0);
    spmm_kernel<<<4096, 256, 0, stream>>>(B1, B2, edge_index, edge_value, filt, 1);
    tail_kernel<<<M_TGT / 4, 256, 0, stream>>>(Xp, B2, lin1_w, lin1_b, lin_w, lin_b,
                                               target_x, out);
}

// Round 2
// 772.728 us; speedup vs baseline: 2.0416x; 2.0416x over previous
//
#include <hip/hip_runtime.h>

// ---- problem constants (from reference) ----
#define N_NODES   100000
#define T_TYPES   4
#define E_EDGES   400000
#define TE_TOT    (T_TYPES * E_EDGES)       // 1,600,000
#define C_CH      2
#define L_LAYERS  2
#define W_INF     128
#define DD        64
#define NUM_CLASS 16
#define BETA      0.5f
#define M_TGT     10000

static const size_t CH_STRIDE = (size_t)N_NODES * DD;   // floats per channel plane

// ---------------------------------------------------------------------------
// filt[l][c][t] = softmax_t(conv_weights[l][c][t])
// ---------------------------------------------------------------------------
__global__ void filt_kernel(const float* __restrict__ cw, float* __restrict__ filt) {
    int r = threadIdx.x;
    if (r < L_LAYERS * C_CH) {
        float v[T_TYPES];
        float m = -1e30f;
        #pragma unroll
        for (int t = 0; t < T_TYPES; ++t) { v[t] = cw[r * T_TYPES + t]; m = fmaxf(m, v[t]); }
        float s = 0.f;
        #pragma unroll
        for (int t = 0; t < T_TYPES; ++t) { v[t] = __expf(v[t] - m); s += v[t]; }
        #pragma unroll
        for (int t = 0; t < T_TYPES; ++t) filt[r * T_TYPES + t] = v[t] / s;
    }
}

// ---------------------------------------------------------------------------
// X_ [c][n][d] = sum_f X[n][f] * Ws[c][f][d]   (both channels fused)
// ---------------------------------------------------------------------------
__global__ __launch_bounds__(256) void proj_kernel(const float* __restrict__ X,
                                                   const float* __restrict__ Ws,
                                                   float* __restrict__ Xp) {
    __shared__ float ws_lds[C_CH * W_INF * DD];   // 64 KB
    int tid = threadIdx.x;
    {
        const float4* g = (const float4*)Ws;
        float4* s = (float4*)ws_lds;
        #pragma unroll
        for (int i = 0; i < 16; ++i) s[tid + 256 * i] = g[tid + 256 * i];
    }
    __syncthreads();

    int d  = tid & 63;
    int r0 = blockIdx.x * 16 + (tid >> 6);
    const float* x0 = X + (size_t)r0 * W_INF;

    float acc0[4] = {0.f, 0.f, 0.f, 0.f};
    float acc1[4] = {0.f, 0.f, 0.f, 0.f};
    for (int f = 0; f < W_INF; ++f) {
        float w0 = ws_lds[f * DD + d];
        float w1 = ws_lds[W_INF * DD + f * DD + d];
        #pragma unroll
        for (int i = 0; i < 4; ++i) {
            float xv = x0[(size_t)(4 * i) * W_INF + f];
            acc0[i] = fmaf(xv, w0, acc0[i]);
            acc1[i] = fmaf(xv, w1, acc1[i]);
        }
    }
    #pragma unroll
    for (int i = 0; i < 4; ++i) {
        size_t o = (size_t)(r0 + 4 * i) * DD + d;
        Xp[o]             = acc0[i];
        Xp[CH_STRIDE + o] = acc1[i];
    }
}

// ---------------------------------------------------------------------------
// CSR build: histogram of destination rows into offs[0..N-1]
// ---------------------------------------------------------------------------
__global__ __launch_bounds__(256) void hist_kernel(const int* __restrict__ edge_index,
                                                   int* __restrict__ offs) {
    int i = blockIdx.x * blockDim.x + threadIdx.x;
    int stride = gridDim.x * blockDim.x;
    for (; i < TE_TOT; i += stride) {
        int t  = i / E_EDGES;
        int ei = i - t * E_EDGES;
        int row = edge_index[(size_t)(t * 2) * E_EDGES + ei];
        atomicAdd(&offs[row], 1);
    }
}

// Block-level exclusive scan (in-place on offs), block totals to partials.
__global__ __launch_bounds__(512) void scan_blocks(int* __restrict__ offs,
                                                   int* __restrict__ partials) {
    __shared__ int s[512];
    int t = threadIdx.x;
    int i = blockIdx.x * 512 + t;
    int x = (i < N_NODES) ? offs[i] : 0;
    s[t] = x; __syncthreads();
    #pragma unroll
    for (int o = 1; o < 512; o <<= 1) {
        int v = (t >= o) ? s[t - o] : 0; __syncthreads();
        s[t] += v; __syncthreads();
    }
    if (i < N_NODES) offs[i] = s[t] - x;          // exclusive within block
    if (t == 511) partials[blockIdx.x] = s[511];  // block total
}

#define NB_SCAN 196   // ceil(100000/512)

__global__ __launch_bounds__(256) void scan_partials(int* __restrict__ partials,
                                                     int* __restrict__ ppref) {
    __shared__ int s[256];
    int t = threadIdx.x;
    int x = (t < NB_SCAN) ? partials[t] : 0;
    s[t] = x; __syncthreads();
    #pragma unroll
    for (int o = 1; o < 256; o <<= 1) {
        int v = (t >= o) ? s[t - o] : 0; __syncthreads();
        s[t] += v; __syncthreads();
    }
    if (t < NB_SCAN) ppref[t] = s[t] - x;         // exclusive across blocks
}

__global__ __launch_bounds__(512) void scan_fixup(int* __restrict__ offs,
                                                  const int* __restrict__ ppref) {
    int i = blockIdx.x * 512 + threadIdx.x;
    if (i < N_NODES) offs[i] += ppref[blockIdx.x];
}

// Scatter edges into CSR slots; offs doubles as cursor (post: offs[r]=orig end).
// edata[pos] = { col | t<<17 , bits(val) }
__global__ __launch_bounds__(256) void scatter_kernel(const int* __restrict__ edge_index,
                                                      const float* __restrict__ edge_value,
                                                      int* __restrict__ offs,
                                                      int2* __restrict__ edata) {
    int i = blockIdx.x * blockDim.x + threadIdx.x;
    int stride = gridDim.x * blockDim.x;
    for (; i < TE_TOT; i += stride) {
        int t  = i / E_EDGES;
        int ei = i - t * E_EDGES;
        int row = edge_index[(size_t)(t * 2) * E_EDGES + ei];
        int col = edge_index[(size_t)(t * 2 + 1) * E_EDGES + ei];
        float v = edge_value[i];
        int pos = atomicAdd(&offs[row], 1);
        edata[pos] = make_int2(col | (t << 17), __float_as_int(v));
    }
}

// ---------------------------------------------------------------------------
// Gather SpMM, both channels fused, one wave per destination row, no atomics.
// After scatter: begin(r) = (r==0 ? 0 : offs[r-1]), end(r) = offs[r].
// ---------------------------------------------------------------------------
__global__ __launch_bounds__(256) void spmm_gather(const float* __restrict__ Hin,
                                                   float* __restrict__ Hout,
                                                   const int* __restrict__ offs,
                                                   const int2* __restrict__ edata,
                                                   const float* __restrict__ filt,
                                                   int layer) {
    int lane = threadIdx.x & 63;
    int row  = (blockIdx.x * blockDim.x + threadIdx.x) >> 6;   // grid sized exactly
    if (row >= N_NODES) return;

    float fl0[T_TYPES], fl1[T_TYPES];
    #pragma unroll
    for (int t = 0; t < T_TYPES; ++t) {
        fl0[t] = filt[layer * C_CH * T_TYPES + t];
        fl1[t] = filt[layer * C_CH * T_TYPES + T_TYPES + t];
    }

    int beg = (row == 0) ? 0 : offs[row - 1];
    int end = offs[row];

    float a0 = 0.f, a1 = 0.f;
    for (int i = beg; i < end; ++i) {
        int2 ed = edata[i];                       // wave-uniform 8B load
        int col = ed.x & 0x1FFFF;
        int t   = ed.x >> 17;
        float v = __int_as_float(ed.y);
        size_t ib = (size_t)col * DD + lane;
        a0 = fmaf(v * fl0[t], Hin[ib], a0);
        a1 = fmaf(v * fl1[t], Hin[CH_STRIDE + ib], a1);
    }
    size_t ob = (size_t)row * DD + lane;
    Hout[ob]             = a0;
    Hout[CH_STRIDE + ob] = a1;
}

// ---------------------------------------------------------------------------
// Tail: 16 targets per block (weights staged once, reused 4x per wave).
// ---------------------------------------------------------------------------
__global__ __launch_bounds__(256) void tail_kernel(const float* __restrict__ Xp,
                                                   const float* __restrict__ H,
                                                   const float* __restrict__ lin1_w,
                                                   const float* __restrict__ lin1_b,
                                                   const float* __restrict__ lin_w,
                                                   const float* __restrict__ lin_b,
                                                   const int* __restrict__ tgt,
                                                   float* __restrict__ out) {
    __shared__ float l1w[W_INF * DD];        // 32 KB
    __shared__ float lw[DD * NUM_CLASS];     // 4 KB
    __shared__ float l1b[DD];
    __shared__ float lb[NUM_CLASS];
    __shared__ float hc[4][W_INF];
    __shared__ float hmid[4][DD];

    int tid = threadIdx.x;
    {
        const float4* g = (const float4*)lin1_w;
        float4* s = (float4*)l1w;
        #pragma unroll
        for (int i = 0; i < 8; ++i) s[tid + 256 * i] = g[tid + 256 * i];
        ((float4*)lw)[tid] = ((const float4*)lin_w)[tid];
        if (tid < DD) l1b[tid] = lin1_b[tid];
        else if (tid < DD + NUM_CLASS) lb[tid - DD] = lin_b[tid - DD];
    }
    __syncthreads();

    int w = tid >> 6, lane = tid & 63;

    #pragma unroll
    for (int g = 0; g < 4; ++g) {
        int m = blockIdx.x * 16 + g * 4 + w;      // M = 10000 = 625*16
        int n = tgt[m];
        size_t b0 = (size_t)n * DD + lane;
        float a = BETA * Xp[b0]             + (1.f - BETA) * H[b0];
        float b = BETA * Xp[CH_STRIDE + b0] + (1.f - BETA) * H[CH_STRIDE + b0];
        hc[w][lane]      = fmaxf(a, 0.f);
        hc[w][DD + lane] = fmaxf(b, 0.f);
        __syncthreads();

        float acc = l1b[lane];
        #pragma unroll 8
        for (int k = 0; k < W_INF; ++k)
            acc = fmaf(hc[w][k], l1w[k * DD + lane], acc);
        hmid[w][lane] = acc;
        __syncthreads();

        if (lane < NUM_CLASS) {
            float o = lb[lane];
            #pragma unroll 8
            for (int k = 0; k < DD; ++k)
                o = fmaf(hmid[w][k], lw[k * NUM_CLASS + lane], o);
            out[(size_t)m * NUM_CLASS + lane] = o;
        }
        __syncthreads();
    }
}

// ---------------------------------------------------------------------------
extern "C" void kernel_launch(void* const* d_in, const int* in_sizes, int n_in,
                              void* d_out, int out_size, void* d_ws, size_t ws_size,
                              hipStream_t stream) {
    const float* X            = (const float*)d_in[0];
    const float* edge_value   = (const float*)d_in[1];
    const float* conv_weights = (const float*)d_in[2];
    const float* Ws           = (const float*)d_in[3];
    const float* lin1_w       = (const float*)d_in[4];
    const float* lin1_b       = (const float*)d_in[5];
    const float* lin_w        = (const float*)d_in[6];
    const float* lin_b        = (const float*)d_in[7];
    const int*   edge_index   = (const int*)d_in[8];
    const int*   target_x     = (const int*)d_in[9];
    float* out = (float*)d_out;

    float* ws   = (float*)d_ws;
    float* Xp   = ws;                          // [C,N,D]  12.8M floats
    float* B1   = ws + 2 * CH_STRIDE;          // [C,N,D]
    float* B2   = ws + 4 * CH_STRIDE;          // [C,N,D]
    float* filt = ws + 6 * CH_STRIDE;          // 16 floats
    int*   offs = (int*)(filt + 32);           // N+1 ints
    int*   partials = offs + N_NODES + 8;      // 196
    int*   ppref    = partials + 256;          // 196
    int2*  edata    = (int2*)(ppref + 256);    // 1.6M int2 = 12.8 MB

    hipMemsetAsync(offs, 0, (N_NODES + 1) * sizeof(int), stream);

    filt_kernel<<<1, 64, 0, stream>>>(conv_weights, filt);
    proj_kernel<<<N_NODES / 16, 256, 0, stream>>>(X, Ws, Xp);
    hist_kernel<<<2048, 256, 0, stream>>>(edge_index, offs);
    scan_blocks<<<NB_SCAN, 512, 0, stream>>>(offs, partials);
    scan_partials<<<1, 256, 0, stream>>>(partials, ppref);
    scan_fixup<<<NB_SCAN, 512, 0, stream>>>(offs, ppref);
    scatter_kernel<<<2048, 256, 0, stream>>>(edge_index, edge_value, offs, edata);
    spmm_gather<<<(N_NODES * 64) / 256, 256, 0, stream>>>(Xp, B1, offs, edata, filt, 0);
    spmm_gather<<<(N_NODES * 64) / 256, 256, 0, stream>>>(B1, B2, offs, edata, filt, 1);
    tail_kernel<<<M_TGT / 16, 256, 0, stream>>>(Xp, B2, lin1_w, lin1_b, lin_w, lin_b,
                                                target_x, out);
}

// Round 3
// 633.756 us; speedup vs baseline: 2.4893x; 1.2193x over previous
//
#include <hip/hip_runtime.h>

// ---- problem constants (from reference) ----
#define N_NODES   100000
#define T_TYPES   4
#define E_EDGES   400000
#define E4        (E_EDGES / 4)             // 100,000 int4 per type-array
#define TE_TOT    (T_TYPES * E_EDGES)       // 1,600,000
#define C_CH      2
#define L_LAYERS  2
#define W_INF     128
#define DD        64
#define NUM_CLASS 16
#define BETA      0.5f
#define M_TGT     10000

// H planes are stored channel-interleaved: H2[n*64 + d] = {ch0, ch1}  (float2)
static const size_t PLANE2 = (size_t)N_NODES * DD;   // float2 elements per buffer

// ---------------------------------------------------------------------------
// X_ [n][d] = { sum_f X[n][f]*Ws[0][f][d] , sum_f X[n][f]*Ws[1][f][d] }
// Ws (64 KB) and a 16-row X tile (8 KB) staged in LDS.
// ---------------------------------------------------------------------------
__global__ __launch_bounds__(256) void proj_kernel(const float* __restrict__ X,
                                                   const float* __restrict__ Ws,
                                                   float2* __restrict__ Xp) {
    __shared__ float ws_lds[C_CH * W_INF * DD];   // 64 KB
    __shared__ float x_lds[16 * W_INF];           // 8 KB
    int tid = threadIdx.x;
    {
        const float4* g = (const float4*)Ws;
        float4* s = (float4*)ws_lds;
        #pragma unroll
        for (int i = 0; i < 16; ++i) s[tid + 256 * i] = g[tid + 256 * i];
        const float4* xg = (const float4*)(X + (size_t)blockIdx.x * 16 * W_INF);
        float4* xs = (float4*)x_lds;
        xs[tid]       = xg[tid];
        xs[tid + 256] = xg[tid + 256];
    }
    __syncthreads();

    int d  = tid & 63;
    int wv = tid >> 6;                            // rows wv, wv+4, wv+8, wv+12
    float acc0[4] = {0.f, 0.f, 0.f, 0.f};
    float acc1[4] = {0.f, 0.f, 0.f, 0.f};
    for (int f = 0; f < W_INF; ++f) {
        float w0 = ws_lds[f * DD + d];
        float w1 = ws_lds[W_INF * DD + f * DD + d];
        #pragma unroll
        for (int i = 0; i < 4; ++i) {
            float xv = x_lds[(wv + 4 * i) * W_INF + f];   // wave-uniform broadcast
            acc0[i] = fmaf(xv, w0, acc0[i]);
            acc1[i] = fmaf(xv, w1, acc1[i]);
        }
    }
    #pragma unroll
    for (int i = 0; i < 4; ++i) {
        size_t r = (size_t)(blockIdx.x * 16 + wv + 4 * i);
        Xp[r * DD + d] = make_float2(acc0[i], acc1[i]);
    }
}

// ---------------------------------------------------------------------------
// CSR build: histogram (int4 reads, 4 edges/thread)
// ---------------------------------------------------------------------------
__global__ __launch_bounds__(256) void hist_kernel(const int* __restrict__ edge_index,
                                                   int* __restrict__ offs) {
    int i = blockIdx.x * blockDim.x + threadIdx.x;
    if (i >= T_TYPES * E4) return;
    int t = i / E4;
    int r = i - t * E4;
    int4 rw = ((const int4*)(edge_index + (size_t)t * 2 * E_EDGES))[r];
    atomicAdd(&offs[rw.x], 1);
    atomicAdd(&offs[rw.y], 1);
    atomicAdd(&offs[rw.z], 1);
    atomicAdd(&offs[rw.w], 1);
}

// Block-level exclusive scan (in-place on offs), block totals to partials.
__global__ __launch_bounds__(512) void scan_blocks(int* __restrict__ offs,
                                                   int* __restrict__ partials) {
    __shared__ int s[512];
    int t = threadIdx.x;
    int i = blockIdx.x * 512 + t;
    int x = (i < N_NODES) ? offs[i] : 0;
    s[t] = x; __syncthreads();
    #pragma unroll
    for (int o = 1; o < 512; o <<= 1) {
        int v = (t >= o) ? s[t - o] : 0; __syncthreads();
        s[t] += v; __syncthreads();
    }
    if (i < N_NODES) offs[i] = s[t] - x;
    if (t == 511) partials[blockIdx.x] = s[511];
}

#define NB_SCAN 196   // ceil(100000/512)

__global__ __launch_bounds__(256) void scan_partials(int* __restrict__ partials,
                                                     int* __restrict__ ppref) {
    __shared__ int s[256];
    int t = threadIdx.x;
    int x = (t < NB_SCAN) ? partials[t] : 0;
    s[t] = x; __syncthreads();
    #pragma unroll
    for (int o = 1; o < 256; o <<= 1) {
        int v = (t >= o) ? s[t - o] : 0; __syncthreads();
        s[t] += v; __syncthreads();
    }
    if (t < NB_SCAN) ppref[t] = s[t] - x;
}

__global__ __launch_bounds__(512) void scan_fixup(int* __restrict__ offs,
                                                  const int* __restrict__ ppref) {
    int i = blockIdx.x * 512 + threadIdx.x;
    if (i < N_NODES) offs[i] += ppref[blockIdx.x];
}

// Scatter edges into CSR slots (int4/float4 reads, 4 edges/thread);
// offs doubles as cursor (post: offs[r] = row end).
// edata[pos] = { col | t<<17 , bits(val) }
__global__ __launch_bounds__(256) void scatter_kernel(const int* __restrict__ edge_index,
                                                      const float* __restrict__ edge_value,
                                                      int* __restrict__ offs,
                                                      int2* __restrict__ edata) {
    int i = blockIdx.x * blockDim.x + threadIdx.x;
    if (i >= T_TYPES * E4) return;
    int t = i / E4;
    int r = i - t * E4;
    const int* base = edge_index + (size_t)t * 2 * E_EDGES;
    int4   rw = ((const int4*)base)[r];
    int4   cl = ((const int4*)(base + E_EDGES))[r];
    float4 vv = ((const float4*)(edge_value + (size_t)t * E_EDGES))[r];
    int tb = t << 17;
    int p0 = atomicAdd(&offs[rw.x], 1);
    edata[p0] = make_int2(cl.x | tb, __float_as_int(vv.x));
    int p1 = atomicAdd(&offs[rw.y], 1);
    edata[p1] = make_int2(cl.y | tb, __float_as_int(vv.y));
    int p2 = atomicAdd(&offs[rw.z], 1);
    edata[p2] = make_int2(cl.z | tb, __float_as_int(vv.z));
    int p3 = atomicAdd(&offs[rw.w], 1);
    edata[p3] = make_int2(cl.w | tb, __float_as_int(vv.w));
}

// ---------------------------------------------------------------------------
// Gather SpMM, channel-interleaved, one wave per destination row, no atomics.
// Each edge: one wave-wide global_load_dwordx2 (512 B contiguous, both chans).
// Softmax filter computed inline from conv_weights (16 values, trivial).
// ---------------------------------------------------------------------------
__global__ __launch_bounds__(256) void spmm_gather(const float2* __restrict__ Hin,
                                                   float2* __restrict__ Hout,
                                                   const int* __restrict__ offs,
                                                   const int2* __restrict__ edata,
                                                   const float* __restrict__ cw,
                                                   int layer) {
    int lane = threadIdx.x & 63;
    int row  = (blockIdx.x * blockDim.x + threadIdx.x) >> 6;   // grid exact

    float f0[T_TYPES], f1[T_TYPES];
    {
        float m0 = -1e30f, m1 = -1e30f;
        #pragma unroll
        for (int t = 0; t < T_TYPES; ++t) {
            f0[t] = cw[layer * C_CH * T_TYPES + t];
            f1[t] = cw[layer * C_CH * T_TYPES + T_TYPES + t];
            m0 = fmaxf(m0, f0[t]); m1 = fmaxf(m1, f1[t]);
        }
        float s0 = 0.f, s1 = 0.f;
        #pragma unroll
        for (int t = 0; t < T_TYPES; ++t) {
            f0[t] = __expf(f0[t] - m0); s0 += f0[t];
            f1[t] = __expf(f1[t] - m1); s1 += f1[t];
        }
        #pragma unroll
        for (int t = 0; t < T_TYPES; ++t) { f0[t] /= s0; f1[t] /= s1; }
    }

    int beg = (row == 0) ? 0 : offs[row - 1];
    int end = offs[row];
    const float2* hp = Hin + lane;

    float a0 = 0.f, a1 = 0.f;
    int i = beg;
    for (; i + 1 < end; i += 2) {
        int2 e0 = edata[i];
        int2 e1 = edata[i + 1];
        int c0 = e0.x & 0x1FFFF, t0 = e0.x >> 17;
        int c1 = e1.x & 0x1FFFF, t1 = e1.x >> 17;
        float2 h0 = hp[(size_t)c0 * DD];
        float2 h1 = hp[(size_t)c1 * DD];
        float v0 = __int_as_float(e0.y);
        float v1 = __int_as_float(e1.y);
        a0 = fmaf(v0 * f0[t0], h0.x, a0);
        a1 = fmaf(v0 * f1[t0], h0.y, a1);
        a0 = fmaf(v1 * f0[t1], h1.x, a0);
        a1 = fmaf(v1 * f1[t1], h1.y, a1);
    }
    if (i < end) {
        int2 e0 = edata[i];
        int c0 = e0.x & 0x1FFFF, t0 = e0.x >> 17;
        float2 h0 = hp[(size_t)c0 * DD];
        float v0 = __int_as_float(e0.y);
        a0 = fmaf(v0 * f0[t0], h0.x, a0);
        a1 = fmaf(v0 * f1[t0], h0.y, a1);
    }
    Hout[(size_t)row * DD + lane] = make_float2(a0, a1);
}

// ---------------------------------------------------------------------------
// Tail: 16 targets per block, channel-interleaved reads.
// ---------------------------------------------------------------------------
__global__ __launch_bounds__(256) void tail_kernel(const float2* __restrict__ Xp,
                                                   const float2* __restrict__ H,
                                                   const float* __restrict__ lin1_w,
                                                   const float* __restrict__ lin1_b,
                                                   const float* __restrict__ lin_w,
                                                   const float* __restrict__ lin_b,
                                                   const int* __restrict__ tgt,
                                                   float* __restrict__ out) {
    __shared__ float l1w[W_INF * DD];        // 32 KB
    __shared__ float lw[DD * NUM_CLASS];     // 4 KB
    __shared__ float l1b[DD];
    __shared__ float lb[NUM_CLASS];
    __shared__ float hc[4][W_INF];
    __shared__ float hmid[4][DD];

    int tid = threadIdx.x;
    {
        const float4* g = (const float4*)lin1_w;
        float4* s = (float4*)l1w;
        #pragma unroll
        for (int i = 0; i < 8; ++i) s[tid + 256 * i] = g[tid + 256 * i];
        ((float4*)lw)[tid] = ((const float4*)lin_w)[tid];
        if (tid < DD) l1b[tid] = lin1_b[tid];
        else if (tid < DD + NUM_CLASS) lb[tid - DD] = lin_b[tid - DD];
    }
    __syncthreads();

    int w = tid >> 6, lane = tid & 63;

    #pragma unroll
    for (int g = 0; g < 4; ++g) {
        int m = blockIdx.x * 16 + g * 4 + w;      // M = 10000 = 625*16
        int n = tgt[m];
        size_t b0 = (size_t)n * DD + lane;
        float2 xp = Xp[b0];
        float2 h  = H[b0];
        float a = BETA * xp.x + (1.f - BETA) * h.x;
        float b = BETA * xp.y + (1.f - BETA) * h.y;
        hc[w][lane]      = fmaxf(a, 0.f);
        hc[w][DD + lane] = fmaxf(b, 0.f);
        __syncthreads();

        float acc = l1b[lane];
        #pragma unroll 8
        for (int k = 0; k < W_INF; ++k)
            acc = fmaf(hc[w][k], l1w[k * DD + lane], acc);
        hmid[w][lane] = acc;
        __syncthreads();

        if (lane < NUM_CLASS) {
            float o = lb[lane];
            #pragma unroll 8
            for (int k = 0; k < DD; ++k)
                o = fmaf(hmid[w][k], lw[k * NUM_CLASS + lane], o);
            out[(size_t)m * NUM_CLASS + lane] = o;
        }
        __syncthreads();
    }
}

// ---------------------------------------------------------------------------
extern "C" void kernel_launch(void* const* d_in, const int* in_sizes, int n_in,
                              void* d_out, int out_size, void* d_ws, size_t ws_size,
                              hipStream_t stream) {
    const float* X            = (const float*)d_in[0];
    const float* edge_value   = (const float*)d_in[1];
    const float* conv_weights = (const float*)d_in[2];
    const float* Ws           = (const float*)d_in[3];
    const float* lin1_w       = (const float*)d_in[4];
    const float* lin1_b       = (const float*)d_in[5];
    const float* lin_w        = (const float*)d_in[6];
    const float* lin_b        = (const float*)d_in[7];
    const int*   edge_index   = (const int*)d_in[8];
    const int*   target_x     = (const int*)d_in[9];
    float* out = (float*)d_out;

    float2* ws2  = (float2*)d_ws;
    float2* Xp   = ws2;                        // [N][D] float2  (51.2 MB)
    float2* B1   = ws2 + PLANE2;               // [N][D] float2
    float2* B2   = ws2 + 2 * PLANE2;           // [N][D] float2
    int*    offs = (int*)(ws2 + 3 * PLANE2);   // N ints
    int*    partials = offs + N_NODES + 8;     // 196
    int*    ppref    = partials + 256;         // 196
    int2*   edata    = (int2*)(ppref + 256);   // 1.6M int2 = 12.8 MB

    hipMemsetAsync(offs, 0, N_NODES * sizeof(int), stream);

    proj_kernel<<<N_NODES / 16, 256, 0, stream>>>(X, Ws, Xp);
    hist_kernel<<<(T_TYPES * E4 + 255) / 256, 256, 0, stream>>>(edge_index, offs);
    scan_blocks<<<NB_SCAN, 512, 0, stream>>>(offs, partials);
    scan_partials<<<1, 256, 0, stream>>>(partials, ppref);
    scan_fixup<<<NB_SCAN, 512, 0, stream>>>(offs, ppref);
    scatter_kernel<<<(T_TYPES * E4 + 255) / 256, 256, 0, stream>>>(edge_index, edge_value,
                                                                   offs, edata);
    spmm_gather<<<(N_NODES * 64) / 256, 256, 0, stream>>>(Xp, B1, offs, edata,
                                                          conv_weights, 0);
    spmm_gather<<<(N_NODES * 64) / 256, 256, 0, stream>>>(B1, B2, offs, edata,
                                                          conv_weights, 1);
    tail_kernel<<<M_TGT / 16, 256, 0, stream>>>(Xp, B2, lin1_w, lin1_b, lin_w, lin_b,
                                                target_x, out);
}

// Round 4
// 386.150 us; speedup vs baseline: 4.0855x; 1.6412x over previous
//
#include <hip/hip_runtime.h>

// ---- problem constants (from reference) ----
#define N_NODES   100000
#define T_TYPES   4
#define E_EDGES   400000
#define E4        100000                    // int4 groups per type-array
#define G_TOT     400000                    // total int4 groups = TE_TOT/4
#define TE_TOT    1600000
#define C_CH      2
#define L_LAYERS  2
#define W_INF     128
#define DD        64
#define NUM_CLASS 16
#define BETA      0.5f
#define M_TGT     10000

// CSR build tiling
#define NBKT      196                       // ceil(100000/512) buckets of 512 rows
#define BROWS     512
#define CHUNK_G   1024                      // int4 groups per partition block (4096 edges)
#define NPART_BLK ((G_TOT + CHUNK_G - 1) / CHUNK_G)   // 391
#define CAPD      10240                     // LDS edge capacity in rowsort (80 KB)

// H planes channel-interleaved: H2[n*64 + d] = {ch0, ch1}
static const size_t PLANE2 = (size_t)N_NODES * DD;

// ---------------------------------------------------------------------------
// X_ [n][d] = { X[n]·Ws[0][:,d] , X[n]·Ws[1][:,d] }; Ws + X tile in LDS.
// ---------------------------------------------------------------------------
__global__ __launch_bounds__(256) void proj_kernel(const float* __restrict__ X,
                                                   const float* __restrict__ Ws,
                                                   float2* __restrict__ Xp) {
    __shared__ float ws_lds[C_CH * W_INF * DD];   // 64 KB
    __shared__ float x_lds[16 * W_INF];           // 8 KB
    int tid = threadIdx.x;
    {
        const float4* g = (const float4*)Ws;
        float4* s = (float4*)ws_lds;
        #pragma unroll
        for (int i = 0; i < 16; ++i) s[tid + 256 * i] = g[tid + 256 * i];
        const float4* xg = (const float4*)(X + (size_t)blockIdx.x * 16 * W_INF);
        float4* xs = (float4*)x_lds;
        xs[tid]       = xg[tid];
        xs[tid + 256] = xg[tid + 256];
    }
    __syncthreads();

    int d  = tid & 63;
    int wv = tid >> 6;
    float acc0[4] = {0.f, 0.f, 0.f, 0.f};
    float acc1[4] = {0.f, 0.f, 0.f, 0.f};
    for (int f = 0; f < W_INF; ++f) {
        float w0 = ws_lds[f * DD + d];
        float w1 = ws_lds[W_INF * DD + f * DD + d];
        #pragma unroll
        for (int i = 0; i < 4; ++i) {
            float xv = x_lds[(wv + 4 * i) * W_INF + f];
            acc0[i] = fmaf(xv, w0, acc0[i]);
            acc1[i] = fmaf(xv, w1, acc1[i]);
        }
    }
    #pragma unroll
    for (int i = 0; i < 4; ++i) {
        size_t r = (size_t)(blockIdx.x * 16 + wv + 4 * i);
        Xp[r * DD + d] = make_float2(acc0[i], acc1[i]);
    }
}

// ---------------------------------------------------------------------------
// Pass A: per-bucket edge histogram (bucket = row >> 9), LDS-staged.
// ---------------------------------------------------------------------------
__global__ __launch_bounds__(256) void bucket_hist(const int* __restrict__ edge_index,
                                                   int* __restrict__ bc) {
    __shared__ int h[NBKT];
    int tid = threadIdx.x;
    if (tid < NBKT) h[tid] = 0;
    __syncthreads();
    #pragma unroll
    for (int g = 0; g < 4; ++g) {
        int idx = blockIdx.x * CHUNK_G + g * 256 + tid;
        if (idx < G_TOT) {
            int t = idx / E4, r = idx - t * E4;
            int4 rw = ((const int4*)(edge_index + (size_t)t * 2 * E_EDGES))[r];
            atomicAdd(&h[rw.x >> 9], 1);
            atomicAdd(&h[rw.y >> 9], 1);
            atomicAdd(&h[rw.z >> 9], 1);
            atomicAdd(&h[rw.w >> 9], 1);
        }
    }
    __syncthreads();
    if (tid < NBKT && h[tid] > 0) atomicAdd(&bc[tid], h[tid]);
}

// ---------------------------------------------------------------------------
// Pass B: exclusive scan of 196 bucket counts -> bases + cursors (1 wave).
// ---------------------------------------------------------------------------
__global__ void bucket_scan(const int* __restrict__ bc, int* __restrict__ bbase,
                            int* __restrict__ cursor) {
    int lane = threadIdx.x;
    if (lane >= 64) return;
    int c[4]; int s = 0;
    #pragma unroll
    for (int k = 0; k < 4; ++k) {
        int idx = lane * 4 + k;
        c[k] = (idx < NBKT) ? bc[idx] : 0;
        s += c[k];
    }
    int inc = s;
    #pragma unroll
    for (int off = 1; off < 64; off <<= 1) {
        int v = __shfl_up(inc, off);
        if (lane >= off) inc += v;
    }
    int base = inc - s;
    #pragma unroll
    for (int k = 0; k < 4; ++k) {
        int idx = lane * 4 + k;
        if (idx < NBKT) { bbase[idx] = base; cursor[idx] = base; }
        base += c[k];
    }
}

// ---------------------------------------------------------------------------
// Pass C: partition edges into buckets. Per block: 4096 edges -> LDS
// bucket-sort -> flush contiguous per-bucket runs via global cursors.
// Packed edge: e.x = col | t<<17 | (row&511)<<19 ; e.y = bits(val)
// ---------------------------------------------------------------------------
__global__ __launch_bounds__(256) void partition_kernel(const int* __restrict__ edge_index,
                                                        const float* __restrict__ edge_value,
                                                        int* __restrict__ cursor,
                                                        int2* __restrict__ tmp) {
    __shared__ int cnt[NBKT];
    __shared__ int lbase[NBKT];
    __shared__ int gbase[NBKT];
    __shared__ int2 le[CHUNK_G * 4];              // 32 KB
    __shared__ unsigned char lbk[CHUNK_G * 4];    // 4 KB
    int tid = threadIdx.x;
    if (tid < NBKT) cnt[tid] = 0;
    __syncthreads();

    int px[16], pv[16], rk[16], bk[16];
    int ne = 0;
    #pragma unroll
    for (int g = 0; g < 4; ++g) {
        int idx = blockIdx.x * CHUNK_G + g * 256 + tid;
        if (idx < G_TOT) {
            int t = idx / E4, r = idx - t * E4;
            const int* bptr = edge_index + (size_t)t * 2 * E_EDGES;
            int4   rw = ((const int4*)bptr)[r];
            int4   cl = ((const int4*)(bptr + E_EDGES))[r];
            float4 vv = ((const float4*)(edge_value + (size_t)t * E_EDGES))[r];
            int tb = t << 17;
            int   rr[4] = {rw.x, rw.y, rw.z, rw.w};
            int   cc[4] = {cl.x, cl.y, cl.z, cl.w};
            float vf[4] = {vv.x, vv.y, vv.z, vv.w};
            #pragma unroll
            for (int k = 0; k < 4; ++k) {
                int b = rr[k] >> 9;
                px[ne] = cc[k] | tb | ((rr[k] & 511) << 19);
                pv[ne] = __float_as_int(vf[k]);
                bk[ne] = b;
                rk[ne] = atomicAdd(&cnt[b], 1);
                ++ne;
            }
        }
    }
    __syncthreads();
    if (tid < 64) {                                // scan cnt -> lbase
        int c[4]; int s = 0;
        #pragma unroll
        for (int k = 0; k < 4; ++k) {
            int idx = tid * 4 + k;
            c[k] = (idx < NBKT) ? cnt[idx] : 0;
            s += c[k];
        }
        int inc = s;
        #pragma unroll
        for (int off = 1; off < 64; off <<= 1) {
            int v = __shfl_up(inc, off);
            if (tid >= off) inc += v;
        }
        int base = inc - s;
        #pragma unroll
        for (int k = 0; k < 4; ++k) {
            int idx = tid * 4 + k;
            if (idx < NBKT) lbase[idx] = base;
            base += c[k];
        }
    }
    __syncthreads();
    #pragma unroll
    for (int k = 0; k < 16; ++k) {
        if (k < ne) {
            int slot = lbase[bk[k]] + rk[k];
            le[slot]  = make_int2(px[k], pv[k]);
            lbk[slot] = (unsigned char)bk[k];
        }
    }
    __syncthreads();
    if (tid < NBKT) gbase[tid] = cnt[tid] ? atomicAdd(&cursor[tid], cnt[tid]) : 0;
    __syncthreads();
    int ngrp = min(CHUNK_G, G_TOT - blockIdx.x * CHUNK_G);
    int nloc = 4 * ngrp;
    for (int j = tid; j < nloc; j += 256) {
        int b = lbk[j];
        tmp[gbase[b] + (j - lbase[b])] = le[j];
    }
}

// ---------------------------------------------------------------------------
// Pass D: per-bucket row-sort in LDS, write final CSR segment (contiguous,
// coalesced) + per-row end offsets. Overflow beyond CAPD reads from global.
// ---------------------------------------------------------------------------
__global__ __launch_bounds__(256) void rowsort_kernel(const int2* __restrict__ tmp,
                                                      const int* __restrict__ bbase,
                                                      const int* __restrict__ bc,
                                                      int2* __restrict__ edata,
                                                      int* __restrict__ offs) {
    __shared__ int rcnt[BROWS];
    __shared__ int rbase[BROWS];
    __shared__ int rcur[BROWS];
    __shared__ int2 le[CAPD];                     // 80 KB
    int b   = blockIdx.x;
    int tid = threadIdx.x;
    int bb  = bbase[b];
    int cnt = bc[b];
    for (int i = tid; i < BROWS; i += 256) rcnt[i] = 0;
    __syncthreads();
    for (int j = tid; j < cnt; j += 256) {
        int2 e = tmp[bb + j];
        if (j < CAPD) le[j] = e;
        atomicAdd(&rcnt[(e.x >> 19) & 511], 1);
    }
    __syncthreads();
    if (tid < 64) {                                // scan 512 row counts
        int c[8]; int s = 0;
        #pragma unroll
        for (int k = 0; k < 8; ++k) { c[k] = rcnt[tid * 8 + k]; s += c[k]; }
        int inc = s;
        #pragma unroll
        for (int off = 1; off < 64; off <<= 1) {
            int v = __shfl_up(inc, off);
            if (tid >= off) inc += v;
        }
        int base = inc - s;
        #pragma unroll
        for (int k = 0; k < 8; ++k) { rbase[tid * 8 + k] = base; base += c[k]; }
    }
    __syncthreads();
    for (int i = tid; i < BROWS; i += 256) rcur[i] = rbase[i];
    __syncthreads();
    for (int j = tid; j < cnt; j += 256) {
        int2 e = (j < CAPD) ? le[j] : tmp[bb + j];
        int lr = (e.x >> 19) & 511;
        int pos = atomicAdd(&rcur[lr], 1);
        edata[bb + pos] = e;
    }
    int row0  = b * BROWS;
    int nrows = min(BROWS, N_NODES - row0);
    for (int lr = tid; lr < nrows; lr += 256)
        offs[row0 + lr] = bb + rbase[lr] + rcnt[lr];
}

// ---------------------------------------------------------------------------
// Layer-1 gather SpMM: one wave per destination row, all N rows.
// ---------------------------------------------------------------------------
__device__ __forceinline__ void load_filter(const float* cw, int layer,
                                            float* f0, float* f1) {
    float m0 = -1e30f, m1 = -1e30f;
    #pragma unroll
    for (int t = 0; t < T_TYPES; ++t) {
        f0[t] = cw[layer * C_CH * T_TYPES + t];
        f1[t] = cw[layer * C_CH * T_TYPES + T_TYPES + t];
        m0 = fmaxf(m0, f0[t]); m1 = fmaxf(m1, f1[t]);
    }
    float s0 = 0.f, s1 = 0.f;
    #pragma unroll
    for (int t = 0; t < T_TYPES; ++t) {
        f0[t] = __expf(f0[t] - m0); s0 += f0[t];
        f1[t] = __expf(f1[t] - m1); s1 += f1[t];
    }
    #pragma unroll
    for (int t = 0; t < T_TYPES; ++t) { f0[t] /= s0; f1[t] /= s1; }
}

__device__ __forceinline__ float2 row_gather(const float2* __restrict__ hp,
                                             const int2* __restrict__ edata,
                                             int beg, int end,
                                             const float* f0, const float* f1) {
    float a0 = 0.f, a1 = 0.f;
    int i = beg;
    for (; i + 1 < end; i += 2) {
        int2 e0 = edata[i];
        int2 e1 = edata[i + 1];
        int c0 = e0.x & 0x1FFFF, t0 = (e0.x >> 17) & 3;
        int c1 = e1.x & 0x1FFFF, t1 = (e1.x >> 17) & 3;
        float2 h0 = hp[(size_t)c0 * DD];
        float2 h1 = hp[(size_t)c1 * DD];
        float v0 = __int_as_float(e0.y);
        float v1 = __int_as_float(e1.y);
        a0 = fmaf(v0 * f0[t0], h0.x, a0);
        a1 = fmaf(v0 * f1[t0], h0.y, a1);
        a0 = fmaf(v1 * f0[t1], h1.x, a0);
        a1 = fmaf(v1 * f1[t1], h1.y, a1);
    }
    if (i < end) {
        int2 e0 = edata[i];
        int c0 = e0.x & 0x1FFFF, t0 = (e0.x >> 17) & 3;
        float2 h0 = hp[(size_t)c0 * DD];
        float v0 = __int_as_float(e0.y);
        a0 = fmaf(v0 * f0[t0], h0.x, a0);
        a1 = fmaf(v0 * f1[t0], h0.y, a1);
    }
    return make_float2(a0, a1);
}

__global__ __launch_bounds__(256) void spmm_gather(const float2* __restrict__ Hin,
                                                   float2* __restrict__ Hout,
                                                   const int* __restrict__ offs,
                                                   const int2* __restrict__ edata,
                                                   const float* __restrict__ cw) {
    int lane = threadIdx.x & 63;
    int row  = (blockIdx.x * blockDim.x + threadIdx.x) >> 6;
    float f0[T_TYPES], f1[T_TYPES];
    load_filter(cw, 0, f0, f1);
    int beg = (row == 0) ? 0 : offs[row - 1];
    int end = offs[row];
    float2 r = row_gather(Hin + lane, edata, beg, end, f0, f1);
    Hout[(size_t)row * DD + lane] = r;
}

// ---------------------------------------------------------------------------
// Layer-2 gather SpMM restricted to target rows: one wave per target m.
// Output compact [M][64] float2.
// ---------------------------------------------------------------------------
__global__ __launch_bounds__(256) void spmm_gather_tgt(const float2* __restrict__ Hin,
                                                       float2* __restrict__ Hout,
                                                       const int* __restrict__ offs,
                                                       const int2* __restrict__ edata,
                                                       const float* __restrict__ cw,
                                                       const int* __restrict__ tgt) {
    int lane = threadIdx.x & 63;
    int m    = (blockIdx.x * blockDim.x + threadIdx.x) >> 6;
    float f0[T_TYPES], f1[T_TYPES];
    load_filter(cw, 1, f0, f1);
    int row = tgt[m];
    int beg = (row == 0) ? 0 : offs[row - 1];
    int end = offs[row];
    float2 r = row_gather(Hin + lane, edata, beg, end, f0, f1);
    Hout[(size_t)m * DD + lane] = r;
}

// ---------------------------------------------------------------------------
// Tail: 16 targets per block; H2 read from compact [M] buffer.
// ---------------------------------------------------------------------------
__global__ __launch_bounds__(256) void tail_kernel(const float2* __restrict__ Xp,
                                                   const float2* __restrict__ H2,
                                                   const float* __restrict__ lin1_w,
                                                   const float* __restrict__ lin1_b,
                                                   const float* __restrict__ lin_w,
                                                   const float* __restrict__ lin_b,
                                                   const int* __restrict__ tgt,
                                                   float* __restrict__ out) {
    __shared__ float l1w[W_INF * DD];        // 32 KB
    __shared__ float lw[DD * NUM_CLASS];     // 4 KB
    __shared__ float l1b[DD];
    __shared__ float lb[NUM_CLASS];
    __shared__ float hc[4][W_INF];
    __shared__ float hmid[4][DD];

    int tid = threadIdx.x;
    {
        const float4* g = (const float4*)lin1_w;
        float4* s = (float4*)l1w;
        #pragma unroll
        for (int i = 0; i < 8; ++i) s[tid + 256 * i] = g[tid + 256 * i];
        ((float4*)lw)[tid] = ((const float4*)lin_w)[tid];
        if (tid < DD) l1b[tid] = lin1_b[tid];
        else if (tid < DD + NUM_CLASS) lb[tid - DD] = lin_b[tid - DD];
    }
    __syncthreads();

    int w = tid >> 6, lane = tid & 63;

    #pragma unroll
    for (int g = 0; g < 4; ++g) {
        int m = blockIdx.x * 16 + g * 4 + w;      // M = 10000 = 625*16
        int n = tgt[m];
        float2 xp = Xp[(size_t)n * DD + lane];
        float2 h  = H2[(size_t)m * DD + lane];
        float a = BETA * xp.x + (1.f - BETA) * h.x;
        float b = BETA * xp.y + (1.f - BETA) * h.y;
        hc[w][lane]      = fmaxf(a, 0.f);
        hc[w][DD + lane] = fmaxf(b, 0.f);
        __syncthreads();

        float acc = l1b[lane];
        #pragma unroll 8
        for (int k = 0; k < W_INF; ++k)
            acc = fmaf(hc[w][k], l1w[k * DD + lane], acc);
        hmid[w][lane] = acc;
        __syncthreads();

        if (lane < NUM_CLASS) {
            float o = lb[lane];
            #pragma unroll 8
            for (int k = 0; k < DD; ++k)
                o = fmaf(hmid[w][k], lw[k * NUM_CLASS + lane], o);
            out[(size_t)m * NUM_CLASS + lane] = o;
        }
        __syncthreads();
    }
}

// ---------------------------------------------------------------------------
extern "C" void kernel_launch(void* const* d_in, const int* in_sizes, int n_in,
                              void* d_out, int out_size, void* d_ws, size_t ws_size,
                              hipStream_t stream) {
    const float* X            = (const float*)d_in[0];
    const float* edge_value   = (const float*)d_in[1];
    const float* conv_weights = (const float*)d_in[2];
    const float* Ws           = (const float*)d_in[3];
    const float* lin1_w       = (const float*)d_in[4];
    const float* lin1_b       = (const float*)d_in[5];
    const float* lin_w        = (const float*)d_in[6];
    const float* lin_b        = (const float*)d_in[7];
    const int*   edge_index   = (const int*)d_in[8];
    const int*   target_x     = (const int*)d_in[9];
    float* out = (float*)d_out;

    float2* ws2  = (float2*)d_ws;
    float2* Xp   = ws2;                           // [N][64] float2 (51.2 MB)
    float2* B1   = ws2 + PLANE2;                  // [N][64] float2 (51.2 MB)
    float2* B2   = ws2 + 2 * PLANE2;              // [M][64] float2 (5.1 MB)
    int* ip      = (int*)(ws2 + 2 * PLANE2 + (size_t)M_TGT * DD);
    int* offs    = ip;                            // N
    int* bc      = offs + N_NODES;                // 256
    int* bbase   = bc + 256;                      // 256
    int* cursor  = bbase + 256;                   // 256
    int2* tmp    = (int2*)(cursor + 256);         // 1.6M int2 (12.8 MB)
    int2* edata  = tmp + TE_TOT;                  // 1.6M int2 (12.8 MB)

    hipMemsetAsync(bc, 0, NBKT * sizeof(int), stream);

    proj_kernel<<<N_NODES / 16, 256, 0, stream>>>(X, Ws, Xp);
    bucket_hist<<<NPART_BLK, 256, 0, stream>>>(edge_index, bc);
    bucket_scan<<<1, 64, 0, stream>>>(bc, bbase, cursor);
    partition_kernel<<<NPART_BLK, 256, 0, stream>>>(edge_index, edge_value, cursor, tmp);
    rowsort_kernel<<<NBKT, 256, 0, stream>>>(tmp, bbase, bc, edata, offs);
    spmm_gather<<<(N_NODES * 64) / 256, 256, 0, stream>>>(Xp, B1, offs, edata,
                                                          conv_weights);
    spmm_gather_tgt<<<(M_TGT * 64) / 256, 256, 0, stream>>>(B1, B2, offs, edata,
                                                            conv_weights, target_x);
    tail_kernel<<<M_TGT / 16, 256, 0, stream>>>(Xp, B2, lin1_w, lin1_b, lin_w, lin_b,
                                                target_x, out);
}

// Round 5
// 358.921 us; speedup vs baseline: 4.3954x; 1.0759x over previous
//
#include <hip/hip_runtime.h>

// ---- problem constants (from reference) ----
#define N_NODES   100000
#define T_TYPES   4
#define E_EDGES   400000
#define E4        100000                    // int4 groups per type-array
#define G_TOT     400000                    // total int4 groups = TE_TOT/4
#define TE_TOT    1600000
#define C_CH      2
#define L_LAYERS  2
#define W_INF     128
#define DD        64
#define NUM_CLASS 16
#define BETA      0.5f
#define M_TGT     10000

// CSR build tiling
#define NBKT      196                       // ceil(100000/512) buckets of 512 rows
#define BROWS     512
#define BPAD      10240                     // padded slots per bucket (mean 8163, sd 90 -> +23 sigma)
#define CHUNK_G   1024                      // int4 groups per partition block (4096 edges)
#define NPART_BLK ((G_TOT + CHUNK_G - 1) / CHUNK_G)   // 391

// H planes channel-interleaved: H2[n*64 + d] = {ch0, ch1}
static const size_t PLANE2 = (size_t)N_NODES * DD;

// ---------------------------------------------------------------------------
// X_ [n][d] = { X[n]·Ws[0][:,d] , X[n]·Ws[1][:,d] }; Ws + X tile in LDS.
// ---------------------------------------------------------------------------
__global__ __launch_bounds__(256) void proj_kernel(const float* __restrict__ X,
                                                   const float* __restrict__ Ws,
                                                   float2* __restrict__ Xp) {
    __shared__ float ws_lds[C_CH * W_INF * DD];   // 64 KB
    __shared__ float x_lds[16 * W_INF];           // 8 KB
    int tid = threadIdx.x;
    {
        const float4* g = (const float4*)Ws;
        float4* s = (float4*)ws_lds;
        #pragma unroll
        for (int i = 0; i < 16; ++i) s[tid + 256 * i] = g[tid + 256 * i];
        const float4* xg = (const float4*)(X + (size_t)blockIdx.x * 16 * W_INF);
        float4* xs = (float4*)x_lds;
        xs[tid]       = xg[tid];
        xs[tid + 256] = xg[tid + 256];
    }
    __syncthreads();

    int d  = tid & 63;
    int wv = tid >> 6;
    float acc0[4] = {0.f, 0.f, 0.f, 0.f};
    float acc1[4] = {0.f, 0.f, 0.f, 0.f};
    for (int f = 0; f < W_INF; ++f) {
        float w0 = ws_lds[f * DD + d];
        float w1 = ws_lds[W_INF * DD + f * DD + d];
        #pragma unroll
        for (int i = 0; i < 4; ++i) {
            float xv = x_lds[(wv + 4 * i) * W_INF + f];
            acc0[i] = fmaf(xv, w0, acc0[i]);
            acc1[i] = fmaf(xv, w1, acc1[i]);
        }
    }
    #pragma unroll
    for (int i = 0; i < 4; ++i) {
        size_t r = (size_t)(blockIdx.x * 16 + wv + 4 * i);
        Xp[r * DD + d] = make_float2(acc0[i], acc1[i]);
    }
}

// ---------------------------------------------------------------------------
// cursor[b] = b * BPAD  (per-bucket write cursors into padded edata)
// ---------------------------------------------------------------------------
__global__ void init_cursor(int* __restrict__ cursor) {
    int i = threadIdx.x;
    if (i < NBKT) cursor[i] = i * BPAD;
}

// ---------------------------------------------------------------------------
// Partition edges into bucket-padded edata. Per block: 4096 edges -> LDS
// bucket-sort -> reserve per-bucket runs via global cursors -> write runs.
// Packed edge: e.x = col | t<<17 | (row&511)<<19 ; e.y = bits(val)
// ---------------------------------------------------------------------------
__global__ __launch_bounds__(256) void partition_kernel(const int* __restrict__ edge_index,
                                                        const float* __restrict__ edge_value,
                                                        int* __restrict__ cursor,
                                                        int2* __restrict__ edata) {
    __shared__ int cnt[NBKT];
    __shared__ int lbase[NBKT];
    __shared__ int gbase[NBKT];
    __shared__ int2 le[CHUNK_G * 4];              // 32 KB
    __shared__ unsigned char lbk[CHUNK_G * 4];    // 4 KB
    int tid = threadIdx.x;
    if (tid < NBKT) cnt[tid] = 0;
    __syncthreads();

    int px[16], pv[16], rk[16], bk[16];
    int ne = 0;
    #pragma unroll
    for (int g = 0; g < 4; ++g) {
        int idx = blockIdx.x * CHUNK_G + g * 256 + tid;
        if (idx < G_TOT) {
            int t = idx / E4, r = idx - t * E4;
            const int* bptr = edge_index + (size_t)t * 2 * E_EDGES;
            int4   rw = ((const int4*)bptr)[r];
            int4   cl = ((const int4*)(bptr + E_EDGES))[r];
            float4 vv = ((const float4*)(edge_value + (size_t)t * E_EDGES))[r];
            int tb = t << 17;
            int   rr[4] = {rw.x, rw.y, rw.z, rw.w};
            int   cc[4] = {cl.x, cl.y, cl.z, cl.w};
            float vf[4] = {vv.x, vv.y, vv.z, vv.w};
            #pragma unroll
            for (int k = 0; k < 4; ++k) {
                int b = rr[k] >> 9;
                px[ne] = cc[k] | tb | ((rr[k] & 511) << 19);
                pv[ne] = __float_as_int(vf[k]);
                bk[ne] = b;
                rk[ne] = atomicAdd(&cnt[b], 1);
                ++ne;
            }
        }
    }
    __syncthreads();
    if (tid < 64) {                                // scan cnt -> lbase
        int c[4]; int s = 0;
        #pragma unroll
        for (int k = 0; k < 4; ++k) {
            int idx = tid * 4 + k;
            c[k] = (idx < NBKT) ? cnt[idx] : 0;
            s += c[k];
        }
        int inc = s;
        #pragma unroll
        for (int off = 1; off < 64; off <<= 1) {
            int v = __shfl_up(inc, off);
            if (tid >= off) inc += v;
        }
        int base = inc - s;
        #pragma unroll
        for (int k = 0; k < 4; ++k) {
            int idx = tid * 4 + k;
            if (idx < NBKT) lbase[idx] = base;
            base += c[k];
        }
    }
    __syncthreads();
    #pragma unroll
    for (int k = 0; k < 16; ++k) {
        if (k < ne) {
            int slot = lbase[bk[k]] + rk[k];
            le[slot]  = make_int2(px[k], pv[k]);
            lbk[slot] = (unsigned char)bk[k];
        }
    }
    __syncthreads();
    if (tid < NBKT) gbase[tid] = cnt[tid] ? atomicAdd(&cursor[tid], cnt[tid]) : 0;
    __syncthreads();
    int ngrp = min(CHUNK_G, G_TOT - blockIdx.x * CHUNK_G);
    int nloc = 4 * ngrp;
    for (int j = tid; j < nloc; j += 256) {
        int b = lbk[j];
        edata[gbase[b] + (j - lbase[b])] = le[j];
    }
}

// ---------------------------------------------------------------------------
// Per-bucket in-LDS row-sort of the bucket-padded edata segment (in place)
// + per-row end offsets. cnt <= BPAD == LDS capacity by construction.
// ---------------------------------------------------------------------------
__global__ __launch_bounds__(256) void rowsort_kernel(const int* __restrict__ cursor,
                                                      int2* __restrict__ edata,
                                                      int* __restrict__ offs) {
    __shared__ int rcnt[BROWS];
    __shared__ int rbase[BROWS];
    __shared__ int rcur[BROWS];
    __shared__ int2 le[BPAD];                     // 80 KB
    int b   = blockIdx.x;
    int tid = threadIdx.x;
    int bb  = b * BPAD;
    int cnt = cursor[b] - bb;
    for (int i = tid; i < BROWS; i += 256) rcnt[i] = 0;
    __syncthreads();
    for (int j = tid; j < cnt; j += 256) {
        int2 e = edata[bb + j];
        le[j] = e;
        atomicAdd(&rcnt[(e.x >> 19) & 511], 1);
    }
    __syncthreads();
    if (tid < 64) {                                // scan 512 row counts
        int c[8]; int s = 0;
        #pragma unroll
        for (int k = 0; k < 8; ++k) { c[k] = rcnt[tid * 8 + k]; s += c[k]; }
        int inc = s;
        #pragma unroll
        for (int off = 1; off < 64; off <<= 1) {
            int v = __shfl_up(inc, off);
            if (tid >= off) inc += v;
        }
        int base = inc - s;
        #pragma unroll
        for (int k = 0; k < 8; ++k) { rbase[tid * 8 + k] = base; base += c[k]; }
    }
    __syncthreads();
    for (int i = tid; i < BROWS; i += 256) rcur[i] = rbase[i];
    __syncthreads();
    for (int j = tid; j < cnt; j += 256) {
        int2 e = le[j];
        int lr = (e.x >> 19) & 511;
        int pos = atomicAdd(&rcur[lr], 1);
        edata[bb + pos] = e;
    }
    int row0  = b * BROWS;
    int nrows = min(BROWS, N_NODES - row0);
    for (int lr = tid; lr < nrows; lr += 256)
        offs[row0 + lr] = bb + rbase[lr] + rcnt[lr];
}

// ---------------------------------------------------------------------------
// SpMM row gather, half-wave scheme: slot = lane&31 covers d = {2s, 2s+1}
// both channels (float4 = 16 B/lane); sub = lane>>5 picks alternating edges.
// One VMEM gather instruction serves TWO edges (1024 B). Partials merged by
// 4 xor-32 shuffles; sub0 half stores the 512 B row.
// ---------------------------------------------------------------------------
__device__ __forceinline__ void load_filter(const float* cw, int layer,
                                            float* f0, float* f1) {
    float m0 = -1e30f, m1 = -1e30f;
    #pragma unroll
    for (int t = 0; t < T_TYPES; ++t) {
        f0[t] = cw[layer * C_CH * T_TYPES + t];
        f1[t] = cw[layer * C_CH * T_TYPES + T_TYPES + t];
        m0 = fmaxf(m0, f0[t]); m1 = fmaxf(m1, f1[t]);
    }
    float s0 = 0.f, s1 = 0.f;
    #pragma unroll
    for (int t = 0; t < T_TYPES; ++t) {
        f0[t] = __expf(f0[t] - m0); s0 += f0[t];
        f1[t] = __expf(f1[t] - m1); s1 += f1[t];
    }
    #pragma unroll
    for (int t = 0; t < T_TYPES; ++t) { f0[t] /= s0; f1[t] /= s1; }
}

__device__ __forceinline__ void row_gather4(const float4* __restrict__ hp4,
                                            const int2* __restrict__ edata,
                                            int beg, int end, int slot, int sub,
                                            const float* f0, const float* f1,
                                            float4& acc) {
    int i = beg + sub;                 // this half-wave's edges: beg+sub, +2, +4...
    for (; i + 2 < end; i += 4) {      // 2 edges per half-wave iteration
        int2 ea = edata[i];
        int2 eb = edata[i + 2];
        int ca = ea.x & 0x1FFFF, ta = (ea.x >> 17) & 3;
        int cb = eb.x & 0x1FFFF, tb = (eb.x >> 17) & 3;
        float4 ha = hp4[(size_t)ca * 32 + slot];
        float4 hb = hp4[(size_t)cb * 32 + slot];
        float va = __int_as_float(ea.y);
        float vb = __int_as_float(eb.y);
        float wa0 = va * f0[ta], wa1 = va * f1[ta];
        float wb0 = vb * f0[tb], wb1 = vb * f1[tb];
        acc.x = fmaf(wa0, ha.x, acc.x);
        acc.y = fmaf(wa1, ha.y, acc.y);
        acc.z = fmaf(wa0, ha.z, acc.z);
        acc.w = fmaf(wa1, ha.w, acc.w);
        acc.x = fmaf(wb0, hb.x, acc.x);
        acc.y = fmaf(wb1, hb.y, acc.y);
        acc.z = fmaf(wb0, hb.z, acc.z);
        acc.w = fmaf(wb1, hb.w, acc.w);
    }
    if (i < end) {
        int2 e = edata[i];
        int c = e.x & 0x1FFFF, t = (e.x >> 17) & 3;
        float4 h = hp4[(size_t)c * 32 + slot];
        float v = __int_as_float(e.y);
        float w0 = v * f0[t], w1 = v * f1[t];
        acc.x = fmaf(w0, h.x, acc.x);
        acc.y = fmaf(w1, h.y, acc.y);
        acc.z = fmaf(w0, h.z, acc.z);
        acc.w = fmaf(w1, h.w, acc.w);
    }
    acc.x += __shfl_xor(acc.x, 32);
    acc.y += __shfl_xor(acc.y, 32);
    acc.z += __shfl_xor(acc.z, 32);
    acc.w += __shfl_xor(acc.w, 32);
}

__device__ __forceinline__ int row_beg(const int* offs, int row) {
    return ((row & 511) == 0) ? (row >> 9) * BPAD : offs[row - 1];
}

__global__ __launch_bounds__(256) void spmm_gather(const float2* __restrict__ Hin,
                                                   float2* __restrict__ Hout,
                                                   const int* __restrict__ offs,
                                                   const int2* __restrict__ edata,
                                                   const float* __restrict__ cw) {
    int lane = threadIdx.x & 63;
    int slot = lane & 31, sub = lane >> 5;
    int row  = (blockIdx.x * blockDim.x + threadIdx.x) >> 6;
    float f0[T_TYPES], f1[T_TYPES];
    load_filter(cw, 0, f0, f1);
    int beg = row_beg(offs, row);
    int end = offs[row];
    float4 acc = make_float4(0.f, 0.f, 0.f, 0.f);
    row_gather4((const float4*)Hin, edata, beg, end, slot, sub, f0, f1, acc);
    if (sub == 0)
        ((float4*)(Hout + (size_t)row * DD))[slot] = acc;
}

__global__ __launch_bounds__(256) void spmm_gather_tgt(const float2* __restrict__ Hin,
                                                       float2* __restrict__ Hout,
                                                       const int* __restrict__ offs,
                                                       const int2* __restrict__ edata,
                                                       const float* __restrict__ cw,
                                                       const int* __restrict__ tgt) {
    int lane = threadIdx.x & 63;
    int slot = lane & 31, sub = lane >> 5;
    int m    = (blockIdx.x * blockDim.x + threadIdx.x) >> 6;
    float f0[T_TYPES], f1[T_TYPES];
    load_filter(cw, 1, f0, f1);
    int row = tgt[m];
    int beg = row_beg(offs, row);
    int end = offs[row];
    float4 acc = make_float4(0.f, 0.f, 0.f, 0.f);
    row_gather4((const float4*)Hin, edata, beg, end, slot, sub, f0, f1, acc);
    if (sub == 0)
        ((float4*)(Hout + (size_t)m * DD))[slot] = acc;
}

// ---------------------------------------------------------------------------
// Tail: 16 targets per block; H2 read from compact [M] buffer.
// ---------------------------------------------------------------------------
__global__ __launch_bounds__(256) void tail_kernel(const float2* __restrict__ Xp,
                                                   const float2* __restrict__ H2,
                                                   const float* __restrict__ lin1_w,
                                                   const float* __restrict__ lin1_b,
                                                   const float* __restrict__ lin_w,
                                                   const float* __restrict__ lin_b,
                                                   const int* __restrict__ tgt,
                                                   float* __restrict__ out) {
    __shared__ float l1w[W_INF * DD];        // 32 KB
    __shared__ float lw[DD * NUM_CLASS];     // 4 KB
    __shared__ float l1b[DD];
    __shared__ float lb[NUM_CLASS];
    __shared__ float hc[4][W_INF];
    __shared__ float hmid[4][DD];

    int tid = threadIdx.x;
    {
        const float4* g = (const float4*)lin1_w;
        float4* s = (float4*)l1w;
        #pragma unroll
        for (int i = 0; i < 8; ++i) s[tid + 256 * i] = g[tid + 256 * i];
        ((float4*)lw)[tid] = ((const float4*)lin_w)[tid];
        if (tid < DD) l1b[tid] = lin1_b[tid];
        else if (tid < DD + NUM_CLASS) lb[tid - DD] = lin_b[tid - DD];
    }
    __syncthreads();

    int w = tid >> 6, lane = tid & 63;

    #pragma unroll
    for (int g = 0; g < 4; ++g) {
        int m = blockIdx.x * 16 + g * 4 + w;      // M = 10000 = 625*16
        int n = tgt[m];
        float2 xp = Xp[(size_t)n * DD + lane];
        float2 h  = H2[(size_t)m * DD + lane];
        float a = BETA * xp.x + (1.f - BETA) * h.x;
        float b = BETA * xp.y + (1.f - BETA) * h.y;
        hc[w][lane]      = fmaxf(a, 0.f);
        hc[w][DD + lane] = fmaxf(b, 0.f);
        __syncthreads();

        float acc = l1b[lane];
        #pragma unroll 8
        for (int k = 0; k < W_INF; ++k)
            acc = fmaf(hc[w][k], l1w[k * DD + lane], acc);
        hmid[w][lane] = acc;
        __syncthreads();

        if (lane < NUM_CLASS) {
            float o = lb[lane];
            #pragma unroll 8
            for (int k = 0; k < DD; ++k)
                o = fmaf(hmid[w][k], lw[k * NUM_CLASS + lane], o);
            out[(size_t)m * NUM_CLASS + lane] = o;
        }
        __syncthreads();
    }
}

// ---------------------------------------------------------------------------
extern "C" void kernel_launch(void* const* d_in, const int* in_sizes, int n_in,
                              void* d_out, int out_size, void* d_ws, size_t ws_size,
                              hipStream_t stream) {
    const float* X            = (const float*)d_in[0];
    const float* edge_value   = (const float*)d_in[1];
    const float* conv_weights = (const float*)d_in[2];
    const float* Ws           = (const float*)d_in[3];
    const float* lin1_w       = (const float*)d_in[4];
    const float* lin1_b       = (const float*)d_in[5];
    const float* lin_w        = (const float*)d_in[6];
    const float* lin_b        = (const float*)d_in[7];
    const int*   edge_index   = (const int*)d_in[8];
    const int*   target_x     = (const int*)d_in[9];
    float* out = (float*)d_out;

    float2* ws2  = (float2*)d_ws;
    float2* Xp   = ws2;                           // [N][64] float2 (51.2 MB)
    float2* B1   = ws2 + PLANE2;                  // [N][64] float2 (51.2 MB)
    float2* B2   = ws2 + 2 * PLANE2;              // [M][64] float2 (5.1 MB)
    int* ip      = (int*)(ws2 + 2 * PLANE2 + (size_t)M_TGT * DD);
    int* offs    = ip;                            // N
    int* cursor  = offs + N_NODES;                // 256
    int2* edata  = (int2*)(cursor + 256);         // NBKT*BPAD int2 (16.1 MB)

    proj_kernel<<<N_NODES / 16, 256, 0, stream>>>(X, Ws, Xp);
    init_cursor<<<1, 256, 0, stream>>>(cursor);
    partition_kernel<<<NPART_BLK, 256, 0, stream>>>(edge_index, edge_value, cursor, edata);
    rowsort_kernel<<<NBKT, 256, 0, stream>>>(cursor, edata, offs);
    spmm_gather<<<(N_NODES * 64) / 256, 256, 0, stream>>>(Xp, B1, offs, edata,
                                                          conv_weights);
    spmm_gather_tgt<<<(M_TGT * 64) / 256, 256, 0, stream>>>(B1, B2, offs, edata,
                                                            conv_weights, target_x);
    tail_kernel<<<M_TGT / 16, 256, 0, stream>>>(Xp, B2, lin1_w, lin1_b, lin_w, lin_b,
                                                target_x, out);
}

// Round 6
// 317.442 us; speedup vs baseline: 4.9697x; 1.1307x over previous
//
#include <hip/hip_runtime.h>

// ---- problem constants (from reference) ----
#define N_NODES   100000
#define T_TYPES   4
#define E_EDGES   400000
#define E4        100000                    // int4 groups per type-array
#define G_TOT     400000                    // total int4 groups = TE_TOT/4
#define TE_TOT    1600000
#define C_CH      2
#define L_LAYERS  2
#define W_INF     128
#define DD        64
#define NUM_CLASS 16
#define BETA      0.5f
#define M_TGT     10000

// CSR build tiling
#define NBKT      196                       // ceil(100000/512) buckets of 512 rows
#define BROWS     512
#define BPAD      9216                      // padded slots/bucket (mean 8163, sd 90 -> +11.7 sigma)
#define CHUNK_G   1024                      // int4 groups per partition block (4096 edges)
#define NPART_BLK ((G_TOT + CHUNK_G - 1) / CHUNK_G)   // 391

// fp32 planes channel-interleaved: [n*64 + d] = {ch0, ch1} (float2)
static const size_t PLANE2 = (size_t)N_NODES * DD;

// bf16 planes: u32 at [n*64 + d] = bf16(ch0) | bf16(ch1)<<16
// gather view: uint2 at [n*32 + slot] covers d = {2s, 2s+1}

__device__ __forceinline__ unsigned bf16rne(float x) {   // RNE f32 -> bf16 bits
    unsigned u = __float_as_uint(x);
    return (u + 0x7FFFu + ((u >> 16) & 1u)) >> 16;
}
__device__ __forceinline__ unsigned packbf(float a, float b) {
    return bf16rne(a) | (bf16rne(b) << 16);
}
__device__ __forceinline__ float bflo(unsigned u) { return __uint_as_float(u << 16); }
__device__ __forceinline__ float bfhi(unsigned u) { return __uint_as_float(u & 0xFFFF0000u); }

// ---------------------------------------------------------------------------
// softmax filter for layer l, both channels
// ---------------------------------------------------------------------------
__device__ __forceinline__ void load_filter(const float* cw, int layer,
                                            float* f0, float* f1) {
    float m0 = -1e30f, m1 = -1e30f;
    #pragma unroll
    for (int t = 0; t < T_TYPES; ++t) {
        f0[t] = cw[layer * C_CH * T_TYPES + t];
        f1[t] = cw[layer * C_CH * T_TYPES + T_TYPES + t];
        m0 = fmaxf(m0, f0[t]); m1 = fmaxf(m1, f1[t]);
    }
    float s0 = 0.f, s1 = 0.f;
    #pragma unroll
    for (int t = 0; t < T_TYPES; ++t) {
        f0[t] = __expf(f0[t] - m0); s0 += f0[t];
        f1[t] = __expf(f1[t] - m1); s1 += f1[t];
    }
    #pragma unroll
    for (int t = 0; t < T_TYPES; ++t) { f0[t] /= s0; f1[t] /= s1; }
}

// ---------------------------------------------------------------------------
// X_ [n][d]: fp32 float2 plane (for tail) + bf16 plane (for layer-1 gather).
// ---------------------------------------------------------------------------
__global__ __launch_bounds__(256) void proj_kernel(const float* __restrict__ X,
                                                   const float* __restrict__ Ws,
                                                   float2* __restrict__ Xp,
                                                   unsigned* __restrict__ Xp16) {
    __shared__ float ws_lds[C_CH * W_INF * DD];   // 64 KB
    __shared__ float x_lds[16 * W_INF];           // 8 KB
    int tid = threadIdx.x;
    {
        const float4* g = (const float4*)Ws;
        float4* s = (float4*)ws_lds;
        #pragma unroll
        for (int i = 0; i < 16; ++i) s[tid + 256 * i] = g[tid + 256 * i];
        const float4* xg = (const float4*)(X + (size_t)blockIdx.x * 16 * W_INF);
        float4* xs = (float4*)x_lds;
        xs[tid]       = xg[tid];
        xs[tid + 256] = xg[tid + 256];
    }
    __syncthreads();

    int d  = tid & 63;
    int wv = tid >> 6;
    float acc0[4] = {0.f, 0.f, 0.f, 0.f};
    float acc1[4] = {0.f, 0.f, 0.f, 0.f};
    for (int f = 0; f < W_INF; ++f) {
        float w0 = ws_lds[f * DD + d];
        float w1 = ws_lds[W_INF * DD + f * DD + d];
        #pragma unroll
        for (int i = 0; i < 4; ++i) {
            float xv = x_lds[(wv + 4 * i) * W_INF + f];
            acc0[i] = fmaf(xv, w0, acc0[i]);
            acc1[i] = fmaf(xv, w1, acc1[i]);
        }
    }
    #pragma unroll
    for (int i = 0; i < 4; ++i) {
        size_t r = (size_t)(blockIdx.x * 16 + wv + 4 * i);
        Xp[r * DD + d]   = make_float2(acc0[i], acc1[i]);
        Xp16[r * DD + d] = packbf(acc0[i], acc1[i]);
    }
}

// ---------------------------------------------------------------------------
// cursor[b] = b * BPAD
// ---------------------------------------------------------------------------
__global__ void init_cursor(int* __restrict__ cursor) {
    int i = threadIdx.x;
    if (i < NBKT) cursor[i] = i * BPAD;
}

// ---------------------------------------------------------------------------
// Partition edges into bucket-padded AoS edata4:
//   edata4[pos] = { col | t<<17 | (row&511)<<19 , bits(val),
//                   bits(val*f0_l1[t]), bits(val*f1_l1[t]) }
// ---------------------------------------------------------------------------
__global__ __launch_bounds__(256) void partition_kernel(const int* __restrict__ edge_index,
                                                        const float* __restrict__ edge_value,
                                                        const float* __restrict__ cw,
                                                        int* __restrict__ cursor,
                                                        int4* __restrict__ edata4) {
    __shared__ int cnt[NBKT];
    __shared__ int lbase[NBKT];
    __shared__ int gbase[NBKT];
    __shared__ int2 le[CHUNK_G * 4];              // 32 KB
    __shared__ unsigned char lbk[CHUNK_G * 4];    // 4 KB
    int tid = threadIdx.x;
    if (tid < NBKT) cnt[tid] = 0;
    __syncthreads();

    float f0[T_TYPES], f1[T_TYPES];
    load_filter(cw, 0, f0, f1);

    int px[16], pv[16], rk[16], bk[16];
    int ne = 0;
    #pragma unroll
    for (int g = 0; g < 4; ++g) {
        int idx = blockIdx.x * CHUNK_G + g * 256 + tid;
        if (idx < G_TOT) {
            int t = idx / E4, r = idx - t * E4;
            const int* bptr = edge_index + (size_t)t * 2 * E_EDGES;
            int4   rw = ((const int4*)bptr)[r];
            int4   cl = ((const int4*)(bptr + E_EDGES))[r];
            float4 vv = ((const float4*)(edge_value + (size_t)t * E_EDGES))[r];
            int tb = t << 17;
            int   rr[4] = {rw.x, rw.y, rw.z, rw.w};
            int   cc[4] = {cl.x, cl.y, cl.z, cl.w};
            float vf[4] = {vv.x, vv.y, vv.z, vv.w};
            #pragma unroll
            for (int k = 0; k < 4; ++k) {
                int b = rr[k] >> 9;
                px[ne] = cc[k] | tb | ((rr[k] & 511) << 19);
                pv[ne] = __float_as_int(vf[k]);
                bk[ne] = b;
                rk[ne] = atomicAdd(&cnt[b], 1);
                ++ne;
            }
        }
    }
    __syncthreads();
    if (tid < 64) {                                // scan cnt -> lbase
        int c[4]; int s = 0;
        #pragma unroll
        for (int k = 0; k < 4; ++k) {
            int idx = tid * 4 + k;
            c[k] = (idx < NBKT) ? cnt[idx] : 0;
            s += c[k];
        }
        int inc = s;
        #pragma unroll
        for (int off = 1; off < 64; off <<= 1) {
            int v = __shfl_up(inc, off);
            if (tid >= off) inc += v;
        }
        int base = inc - s;
        #pragma unroll
        for (int k = 0; k < 4; ++k) {
            int idx = tid * 4 + k;
            if (idx < NBKT) lbase[idx] = base;
            base += c[k];
        }
    }
    __syncthreads();
    #pragma unroll
    for (int k = 0; k < 16; ++k) {
        if (k < ne) {
            int slot = lbase[bk[k]] + rk[k];
            le[slot]  = make_int2(px[k], pv[k]);
            lbk[slot] = (unsigned char)bk[k];
        }
    }
    __syncthreads();
    if (tid < NBKT) gbase[tid] = cnt[tid] ? atomicAdd(&cursor[tid], cnt[tid]) : 0;
    __syncthreads();
    int ngrp = min(CHUNK_G, G_TOT - blockIdx.x * CHUNK_G);
    int nloc = 4 * ngrp;
    for (int j = tid; j < nloc; j += 256) {
        int b = lbk[j];
        int2 e = le[j];
        int t = (e.x >> 17) & 3;
        float v = __int_as_float(e.y);
        edata4[gbase[b] + (j - lbase[b])] =
            make_int4(e.x, e.y, __float_as_int(v * f0[t]), __float_as_int(v * f1[t]));
    }
}

// ---------------------------------------------------------------------------
// Per-bucket in-LDS row-sort of the padded edata4 segment (in place)
// + per-row end offsets. 153.6 KB LDS -> 1 block/CU, 196 blocks.
// ---------------------------------------------------------------------------
__global__ __launch_bounds__(256) void rowsort_kernel(const int* __restrict__ cursor,
                                                      int4* __restrict__ edata4,
                                                      int* __restrict__ offs) {
    __shared__ int rcnt[BROWS];
    __shared__ int rbase[BROWS];
    __shared__ int rcur[BROWS];
    __shared__ int4 le[BPAD];                     // 147456 B
    int b   = blockIdx.x;
    int tid = threadIdx.x;
    int bb  = b * BPAD;
    int cnt = cursor[b] - bb;
    for (int i = tid; i < BROWS; i += 256) rcnt[i] = 0;
    __syncthreads();
    for (int j = tid; j < cnt; j += 256) {
        int4 e = edata4[bb + j];
        le[j] = e;
        atomicAdd(&rcnt[(e.x >> 19) & 511], 1);
    }
    __syncthreads();
    if (tid < 64) {                                // scan 512 row counts
        int c[8]; int s = 0;
        #pragma unroll
        for (int k = 0; k < 8; ++k) { c[k] = rcnt[tid * 8 + k]; s += c[k]; }
        int inc = s;
        #pragma unroll
        for (int off = 1; off < 64; off <<= 1) {
            int v = __shfl_up(inc, off);
            if (tid >= off) inc += v;
        }
        int base = inc - s;
        #pragma unroll
        for (int k = 0; k < 8; ++k) { rbase[tid * 8 + k] = base; base += c[k]; }
    }
    __syncthreads();
    for (int i = tid; i < BROWS; i += 256) rcur[i] = rbase[i];
    __syncthreads();
    for (int j = tid; j < cnt; j += 256) {
        int4 e = le[j];
        int lr = (e.x >> 19) & 511;
        int pos = atomicAdd(&rcur[lr], 1);
        edata4[bb + pos] = e;
    }
    int row0  = b * BROWS;
    int nrows = min(BROWS, N_NODES - row0);
    for (int lr = tid; lr < nrows; lr += 256)
        offs[row0 + lr] = bb + rbase[lr] + rcnt[lr];
}

// ---------------------------------------------------------------------------
// bf16 gather core: half-wave scheme (slot=lane&31 covers d={2s,2s+1} both
// channels as uint2 = 8 B/lane -> 256 B per edge per half-wave; sub=lane>>5
// interleaves edges). Unrolled 4 edges per half-wave iteration.
// ---------------------------------------------------------------------------
__device__ __forceinline__ void edge_fma(const uint2 h, int wb0, int wb1, float4& acc) {
    float w0 = __int_as_float(wb0), w1 = __int_as_float(wb1);
    acc.x = fmaf(w0, bflo(h.x), acc.x);
    acc.y = fmaf(w1, bfhi(h.x), acc.y);
    acc.z = fmaf(w0, bflo(h.y), acc.z);
    acc.w = fmaf(w1, bfhi(h.y), acc.w);
}

__device__ __forceinline__ void row_gather16(const uint2* __restrict__ hp,
                                             const int4* __restrict__ edata4,
                                             int beg, int end, int slot, int sub,
                                             float4& acc) {
    int i = beg + sub;
    for (; i + 6 < end; i += 8) {                 // 4 edges per half-wave iter
        int4 e0 = edata4[i];
        int4 e1 = edata4[i + 2];
        int4 e2 = edata4[i + 4];
        int4 e3 = edata4[i + 6];
        uint2 h0 = hp[(size_t)((e0.x & 0x1FFFF) * 32 + slot)];
        uint2 h1 = hp[(size_t)((e1.x & 0x1FFFF) * 32 + slot)];
        uint2 h2 = hp[(size_t)((e2.x & 0x1FFFF) * 32 + slot)];
        uint2 h3 = hp[(size_t)((e3.x & 0x1FFFF) * 32 + slot)];
        edge_fma(h0, e0.z, e0.w, acc);
        edge_fma(h1, e1.z, e1.w, acc);
        edge_fma(h2, e2.z, e2.w, acc);
        edge_fma(h3, e3.z, e3.w, acc);
    }
    for (; i < end; i += 2) {
        int4 e = edata4[i];
        uint2 h = hp[(size_t)((e.x & 0x1FFFF) * 32 + slot)];
        edge_fma(h, e.z, e.w, acc);
    }
    acc.x += __shfl_xor(acc.x, 32);
    acc.y += __shfl_xor(acc.y, 32);
    acc.z += __shfl_xor(acc.z, 32);
    acc.w += __shfl_xor(acc.w, 32);
}

__device__ __forceinline__ int row_beg(const int* offs, int row) {
    return ((row & 511) == 0) ? (row >> 9) * BPAD : offs[row - 1];
}

// Layer 1: all N rows; bf16 in (Xp16), bf16 out (H116).
__global__ __launch_bounds__(256) void spmm_gather(const uint2* __restrict__ Hin16,
                                                   uint2* __restrict__ Hout16,
                                                   const int* __restrict__ offs,
                                                   const int4* __restrict__ edata4) {
    int lane = threadIdx.x & 63;
    int slot = lane & 31, sub = lane >> 5;
    int row  = (blockIdx.x * blockDim.x + threadIdx.x) >> 6;
    int beg = row_beg(offs, row);
    int end = offs[row];
    float4 acc = make_float4(0.f, 0.f, 0.f, 0.f);
    row_gather16(Hin16, edata4, beg, end, slot, sub, acc);
    if (sub == 0)
        Hout16[(size_t)row * 32 + slot] = make_uint2(packbf(acc.x, acc.y),
                                                     packbf(acc.z, acc.w));
}

// Layer 2: target rows only; bf16 in (H116), fp32 out (compact [M][64] float2).
__global__ __launch_bounds__(256) void spmm_gather_tgt(const uint2* __restrict__ Hin16,
                                                       float2* __restrict__ Hout,
                                                       const int* __restrict__ offs,
                                                       const int4* __restrict__ edata4,
                                                       const float* __restrict__ cw,
                                                       const int* __restrict__ tgt) {
    int lane = threadIdx.x & 63;
    int slot = lane & 31, sub = lane >> 5;
    int m    = (blockIdx.x * blockDim.x + threadIdx.x) >> 6;
    float f0[T_TYPES], f1[T_TYPES];
    load_filter(cw, 1, f0, f1);
    int row = tgt[m];
    int beg = row_beg(offs, row);
    int end = offs[row];
    float4 acc = make_float4(0.f, 0.f, 0.f, 0.f);
    for (int i = beg + sub; i < end; i += 2) {
        int4 e = edata4[i];
        int t = (e.x >> 17) & 3;
        float v = __int_as_float(e.y);
        uint2 h = Hin16[(size_t)((e.x & 0x1FFFF) * 32 + slot)];
        float w0 = v * f0[t], w1 = v * f1[t];
        acc.x = fmaf(w0, bflo(h.x), acc.x);
        acc.y = fmaf(w1, bfhi(h.x), acc.y);
        acc.z = fmaf(w0, bflo(h.y), acc.z);
        acc.w = fmaf(w1, bfhi(h.y), acc.w);
    }
    acc.x += __shfl_xor(acc.x, 32);
    acc.y += __shfl_xor(acc.y, 32);
    acc.z += __shfl_xor(acc.z, 32);
    acc.w += __shfl_xor(acc.w, 32);
    if (sub == 0)
        ((float4*)(Hout + (size_t)m * DD))[slot] = acc;
}

// ---------------------------------------------------------------------------
// Tail: 16 targets per block; H2 from compact fp32 buffer, Xp fp32.
// ---------------------------------------------------------------------------
__global__ __launch_bounds__(256) void tail_kernel(const float2* __restrict__ Xp,
                                                   const float2* __restrict__ H2,
                                                   const float* __restrict__ lin1_w,
                                                   const float* __restrict__ lin1_b,
                                                   const float* __restrict__ lin_w,
                                                   const float* __restrict__ lin_b,
                                                   const int* __restrict__ tgt,
                                                   float* __restrict__ out) {
    __shared__ float l1w[W_INF * DD];        // 32 KB
    __shared__ float lw[DD * NUM_CLASS];     // 4 KB
    __shared__ float l1b[DD];
    __shared__ float lb[NUM_CLASS];
    __shared__ float hc[4][W_INF];
    __shared__ float hmid[4][DD];

    int tid = threadIdx.x;
    {
        const float4* g = (const float4*)lin1_w;
        float4* s = (float4*)l1w;
        #pragma unroll
        for (int i = 0; i < 8; ++i) s[tid + 256 * i] = g[tid + 256 * i];
        ((float4*)lw)[tid] = ((const float4*)lin_w)[tid];
        if (tid < DD) l1b[tid] = lin1_b[tid];
        else if (tid < DD + NUM_CLASS) lb[tid - DD] = lin_b[tid - DD];
    }
    __syncthreads();

    int w = tid >> 6, lane = tid & 63;

    #pragma unroll
    for (int g = 0; g < 4; ++g) {
        int m = blockIdx.x * 16 + g * 4 + w;      // M = 10000 = 625*16
        int n = tgt[m];
        float2 xp = Xp[(size_t)n * DD + lane];
        float2 h  = H2[(size_t)m * DD + lane];
        float a = BETA * xp.x + (1.f - BETA) * h.x;
        float b = BETA * xp.y + (1.f - BETA) * h.y;
        hc[w][lane]      = fmaxf(a, 0.f);
        hc[w][DD + lane] = fmaxf(b, 0.f);
        __syncthreads();

        float acc = l1b[lane];
        #pragma unroll 8
        for (int k = 0; k < W_INF; ++k)
            acc = fmaf(hc[w][k], l1w[k * DD + lane], acc);
        hmid[w][lane] = acc;
        __syncthreads();

        if (lane < NUM_CLASS) {
            float o = lb[lane];
            #pragma unroll 8
            for (int k = 0; k < DD; ++k)
                o = fmaf(hmid[w][k], lw[k * NUM_CLASS + lane], o);
            out[(size_t)m * NUM_CLASS + lane] = o;
        }
        __syncthreads();
    }
}

// ---------------------------------------------------------------------------
extern "C" void kernel_launch(void* const* d_in, const int* in_sizes, int n_in,
                              void* d_out, int out_size, void* d_ws, size_t ws_size,
                              hipStream_t stream) {
    const float* X            = (const float*)d_in[0];
    const float* edge_value   = (const float*)d_in[1];
    const float* conv_weights = (const float*)d_in[2];
    const float* Ws           = (const float*)d_in[3];
    const float* lin1_w       = (const float*)d_in[4];
    const float* lin1_b       = (const float*)d_in[5];
    const float* lin_w        = (const float*)d_in[6];
    const float* lin_b        = (const float*)d_in[7];
    const int*   edge_index   = (const int*)d_in[8];
    const int*   target_x     = (const int*)d_in[9];
    float* out = (float*)d_out;

    float2*   ws2  = (float2*)d_ws;
    float2*   Xp   = ws2;                               // [N][64] float2 (51.2 MB)
    float2*   B2   = ws2 + PLANE2;                      // [M][64] float2 (5.1 MB)
    unsigned* Xp16 = (unsigned*)(ws2 + PLANE2 + (size_t)M_TGT * DD);  // 25.6 MB
    unsigned* H116 = Xp16 + PLANE2;                     // 25.6 MB
    int*      offs = (int*)(H116 + PLANE2);             // N ints
    int*      cursor = offs + N_NODES;                  // 256
    int4*     edata4 = (int4*)(cursor + 256);           // NBKT*BPAD int4 (28.9 MB)

    proj_kernel<<<N_NODES / 16, 256, 0, stream>>>(X, Ws, Xp, Xp16);
    init_cursor<<<1, 256, 0, stream>>>(cursor);
    partition_kernel<<<NPART_BLK, 256, 0, stream>>>(edge_index, edge_value,
                                                    conv_weights, cursor, edata4);
    rowsort_kernel<<<NBKT, 256, 0, stream>>>(cursor, edata4, offs);
    spmm_gather<<<(N_NODES * 64) / 256, 256, 0, stream>>>((const uint2*)Xp16,
                                                          (uint2*)H116, offs, edata4);
    spmm_gather_tgt<<<(M_TGT * 64) / 256, 256, 0, stream>>>((const uint2*)H116, B2,
                                                            offs, edata4,
                                                            conv_weights, target_x);
    tail_kernel<<<M_TGT / 16, 256, 0, stream>>>(Xp, B2, lin1_w, lin1_b, lin_w, lin_b,
                                                target_x, out);
}

// Round 7
// 279.525 us; speedup vs baseline: 5.6439x; 1.1356x over previous
//
#include <hip/hip_runtime.h>

// ---- problem constants (from reference) ----
#define N_NODES   100000
#define T_TYPES   4
#define E_EDGES   400000
#define E4        100000                    // int4 groups per type-array
#define G_TOT     400000                    // total int4 groups = TE_TOT/4
#define TE_TOT    1600000
#define C_CH      2
#define L_LAYERS  2
#define W_INF     128
#define DD        64
#define NUM_CLASS 16
#define BETA      0.5f
#define M_TGT     10000

// CSR build tiling
#define NBKT      196                       // ceil(100000/512) buckets of 512 rows
#define BROWS     512
#define BPAD      9216                      // padded slots/bucket (mean 8163, sd 90 -> +11.7 sigma)
#define CHUNK_G   1024                      // int4 groups per partition block (4096 edges)
#define NPART_BLK ((G_TOT + CHUNK_G - 1) / CHUNK_G)   // 391

// bf16 planes: u32 at [n*64 + d] = bf16(ch0) | bf16(ch1)<<16
// gather view: uint2 at [n*32 + slot] covers d = {2s, 2s+1}
static const size_t PLANE2 = (size_t)N_NODES * DD;    // u32 elements per plane

typedef __attribute__((ext_vector_type(8))) short short8x;   // 8 bf16 (4 VGPRs)
typedef __attribute__((ext_vector_type(4))) float f32x4;     // MFMA C/D

__device__ __forceinline__ unsigned bf16rne(float x) {   // RNE f32 -> bf16 bits
    unsigned u = __float_as_uint(x);
    return (u + 0x7FFFu + ((u >> 16) & 1u)) >> 16;
}
__device__ __forceinline__ unsigned packbf(float a, float b) {
    return bf16rne(a) | (bf16rne(b) << 16);
}
__device__ __forceinline__ float bflo(unsigned u) { return __uint_as_float(u << 16); }
__device__ __forceinline__ float bfhi(unsigned u) { return __uint_as_float(u & 0xFFFF0000u); }

// ---------------------------------------------------------------------------
// softmax filter for layer l, both channels
// ---------------------------------------------------------------------------
__device__ __forceinline__ void load_filter(const float* cw, int layer,
                                            float* f0, float* f1) {
    float m0 = -1e30f, m1 = -1e30f;
    #pragma unroll
    for (int t = 0; t < T_TYPES; ++t) {
        f0[t] = cw[layer * C_CH * T_TYPES + t];
        f1[t] = cw[layer * C_CH * T_TYPES + T_TYPES + t];
        m0 = fmaxf(m0, f0[t]); m1 = fmaxf(m1, f1[t]);
    }
    float s0 = 0.f, s1 = 0.f;
    #pragma unroll
    for (int t = 0; t < T_TYPES; ++t) {
        f0[t] = __expf(f0[t] - m0); s0 += f0[t];
        f1[t] = __expf(f1[t] - m1); s1 += f1[t];
    }
    #pragma unroll
    for (int t = 0; t < T_TYPES; ++t) { f0[t] /= s0; f1[t] /= s1; }
}

// ---------------------------------------------------------------------------
// Wsb[c][d][k] = bf16(Ws[c][k][d])  — B-operand-friendly transpose, 32 KB.
// ---------------------------------------------------------------------------
__global__ void wsb_prep(const float* __restrict__ Ws, unsigned short* __restrict__ Wsb) {
    int idx = blockIdx.x * 256 + threadIdx.x;
    if (idx < C_CH * W_INF * DD) {
        int c   = idx >> 13;
        int rem = idx & 8191;
        int d   = rem >> 7;
        int k   = rem & 127;
        Wsb[idx] = (unsigned short)bf16rne(Ws[c * (W_INF * DD) + k * DD + d]);
    }
}

// ---------------------------------------------------------------------------
// MFMA projection: Xp16[n][d] = pack(bf16(X[n]·Ws[0][:,d]), bf16(X[n]·Ws[1][:,d]))
// Block = 4 waves = 64 rows; wave = one 16-row tile.
// A: X rows from LDS (A[m=lane&15][k=quad*8+j]); B: Wsb from global
// (B[k=quad*8+j][n=lane&15]); C/D: col=lane&15, row=quad*4+reg.
// ---------------------------------------------------------------------------
#define AROW 136   // LDS row pitch in shorts (128 + 8 pad -> 2-way-free frag reads)
__global__ __launch_bounds__(256) void proj_mfma(const float* __restrict__ X,
                                                 const unsigned short* __restrict__ Wsb,
                                                 unsigned* __restrict__ Xp16) {
    __shared__ unsigned short a_lds[64 * AROW];   // 17408 B
    int tid  = threadIdx.x;
    int row0 = blockIdx.x * 64;

    // stage 64x128 fp32 -> bf16 LDS (guard OOB rows with zeros)
    const float4* X4 = (const float4*)X;
    #pragma unroll
    for (int i = 0; i < 8; ++i) {
        int gi = tid + 256 * i;          // float4 index within tile (2048 total)
        int r  = gi >> 5;
        int c4 = gi & 31;
        int row = row0 + r;
        float4 v = make_float4(0.f, 0.f, 0.f, 0.f);
        if (row < N_NODES) v = X4[(size_t)row * 32 + c4];
        *(uint2*)&a_lds[r * AROW + c4 * 4] = make_uint2(packbf(v.x, v.y),
                                                        packbf(v.z, v.w));
    }
    __syncthreads();

    int wave = tid >> 6, lane = tid & 63;
    int m = lane & 15, q = lane >> 4;

    short8x A[4];
    #pragma unroll
    for (int ks = 0; ks < 4; ++ks)
        A[ks] = *(const short8x*)&a_lds[(wave * 16 + m) * AROW + ks * 32 + q * 8];

    #pragma unroll
    for (int ct = 0; ct < 4; ++ct) {
        f32x4 acc0 = {0.f, 0.f, 0.f, 0.f};
        f32x4 acc1 = {0.f, 0.f, 0.f, 0.f};
        #pragma unroll
        for (int ks = 0; ks < 4; ++ks) {
            short8x B0 = *(const short8x*)(Wsb + (ct * 16 + m) * 128 + ks * 32 + q * 8);
            short8x B1 = *(const short8x*)(Wsb + 8192 + (ct * 16 + m) * 128 + ks * 32 + q * 8);
            acc0 = __builtin_amdgcn_mfma_f32_16x16x32_bf16(A[ks], B0, acc0, 0, 0, 0);
            acc1 = __builtin_amdgcn_mfma_f32_16x16x32_bf16(A[ks], B1, acc1, 0, 0, 0);
        }
        #pragma unroll
        for (int r = 0; r < 4; ++r) {
            int row = row0 + wave * 16 + q * 4 + r;
            if (row < N_NODES)
                Xp16[(size_t)row * DD + ct * 16 + m] = packbf(acc0[r], acc1[r]);
        }
    }
}

// ---------------------------------------------------------------------------
// cursor[b] = b * BPAD
// ---------------------------------------------------------------------------
__global__ void init_cursor(int* __restrict__ cursor) {
    int i = threadIdx.x;
    if (i < NBKT) cursor[i] = i * BPAD;
}

// ---------------------------------------------------------------------------
// Partition edges into bucket-padded AoS edata4:
//   edata4[pos] = { col | t<<17 | (row&511)<<19 , bits(val),
//                   bits(val*f0_l1[t]), bits(val*f1_l1[t]) }
// ---------------------------------------------------------------------------
__global__ __launch_bounds__(256) void partition_kernel(const int* __restrict__ edge_index,
                                                        const float* __restrict__ edge_value,
                                                        const float* __restrict__ cw,
                                                        int* __restrict__ cursor,
                                                        int4* __restrict__ edata4) {
    __shared__ int cnt[NBKT];
    __shared__ int lbase[NBKT];
    __shared__ int gbase[NBKT];
    __shared__ int2 le[CHUNK_G * 4];              // 32 KB
    __shared__ unsigned char lbk[CHUNK_G * 4];    // 4 KB
    int tid = threadIdx.x;
    if (tid < NBKT) cnt[tid] = 0;
    __syncthreads();

    float f0[T_TYPES], f1[T_TYPES];
    load_filter(cw, 0, f0, f1);

    int px[16], pv[16], rk[16], bk[16];
    int ne = 0;
    #pragma unroll
    for (int g = 0; g < 4; ++g) {
        int idx = blockIdx.x * CHUNK_G + g * 256 + tid;
        if (idx < G_TOT) {
            int t = idx / E4, r = idx - t * E4;
            const int* bptr = edge_index + (size_t)t * 2 * E_EDGES;
            int4   rw = ((const int4*)bptr)[r];
            int4   cl = ((const int4*)(bptr + E_EDGES))[r];
            float4 vv = ((const float4*)(edge_value + (size_t)t * E_EDGES))[r];
            int tb = t << 17;
            int   rr[4] = {rw.x, rw.y, rw.z, rw.w};
            int   cc[4] = {cl.x, cl.y, cl.z, cl.w};
            float vf[4] = {vv.x, vv.y, vv.z, vv.w};
            #pragma unroll
            for (int k = 0; k < 4; ++k) {
                int b = rr[k] >> 9;
                px[ne] = cc[k] | tb | ((rr[k] & 511) << 19);
                pv[ne] = __float_as_int(vf[k]);
                bk[ne] = b;
                rk[ne] = atomicAdd(&cnt[b], 1);
                ++ne;
            }
        }
    }
    __syncthreads();
    if (tid < 64) {                                // scan cnt -> lbase
        int c[4]; int s = 0;
        #pragma unroll
        for (int k = 0; k < 4; ++k) {
            int idx = tid * 4 + k;
            c[k] = (idx < NBKT) ? cnt[idx] : 0;
            s += c[k];
        }
        int inc = s;
        #pragma unroll
        for (int off = 1; off < 64; off <<= 1) {
            int v = __shfl_up(inc, off);
            if (tid >= off) inc += v;
        }
        int base = inc - s;
        #pragma unroll
        for (int k = 0; k < 4; ++k) {
            int idx = tid * 4 + k;
            if (idx < NBKT) lbase[idx] = base;
            base += c[k];
        }
    }
    __syncthreads();
    #pragma unroll
    for (int k = 0; k < 16; ++k) {
        if (k < ne) {
            int slot = lbase[bk[k]] + rk[k];
            le[slot]  = make_int2(px[k], pv[k]);
            lbk[slot] = (unsigned char)bk[k];
        }
    }
    __syncthreads();
    if (tid < NBKT) gbase[tid] = cnt[tid] ? atomicAdd(&cursor[tid], cnt[tid]) : 0;
    __syncthreads();
    int ngrp = min(CHUNK_G, G_TOT - blockIdx.x * CHUNK_G);
    int nloc = 4 * ngrp;
    for (int j = tid; j < nloc; j += 256) {
        int b = lbk[j];
        int2 e = le[j];
        int t = (e.x >> 17) & 3;
        float v = __int_as_float(e.y);
        edata4[gbase[b] + (j - lbase[b])] =
            make_int4(e.x, e.y, __float_as_int(v * f0[t]), __float_as_int(v * f1[t]));
    }
}

// ---------------------------------------------------------------------------
// Per-bucket in-LDS row-sort of the padded edata4 segment (in place)
// + per-row end offsets. 147 KB LDS -> 1 block/CU, 196 blocks.
// ---------------------------------------------------------------------------
__global__ __launch_bounds__(256) void rowsort_kernel(const int* __restrict__ cursor,
                                                      int4* __restrict__ edata4,
                                                      int* __restrict__ offs) {
    __shared__ int rcnt[BROWS];
    __shared__ int rbase[BROWS];
    __shared__ int rcur[BROWS];
    __shared__ int4 le[BPAD];                     // 147456 B
    int b   = blockIdx.x;
    int tid = threadIdx.x;
    int bb  = b * BPAD;
    int cnt = cursor[b] - bb;
    for (int i = tid; i < BROWS; i += 256) rcnt[i] = 0;
    __syncthreads();
    for (int j = tid; j < cnt; j += 256) {
        int4 e = edata4[bb + j];
        le[j] = e;
        atomicAdd(&rcnt[(e.x >> 19) & 511], 1);
    }
    __syncthreads();
    if (tid < 64) {                                // scan 512 row counts
        int c[8]; int s = 0;
        #pragma unroll
        for (int k = 0; k < 8; ++k) { c[k] = rcnt[tid * 8 + k]; s += c[k]; }
        int inc = s;
        #pragma unroll
        for (int off = 1; off < 64; off <<= 1) {
            int v = __shfl_up(inc, off);
            if (tid >= off) inc += v;
        }
        int base = inc - s;
        #pragma unroll
        for (int k = 0; k < 8; ++k) { rbase[tid * 8 + k] = base; base += c[k]; }
    }
    __syncthreads();
    for (int i = tid; i < BROWS; i += 256) rcur[i] = rbase[i];
    __syncthreads();
    for (int j = tid; j < cnt; j += 256) {
        int4 e = le[j];
        int lr = (e.x >> 19) & 511;
        int pos = atomicAdd(&rcur[lr], 1);
        edata4[bb + pos] = e;
    }
    int row0  = b * BROWS;
    int nrows = min(BROWS, N_NODES - row0);
    for (int lr = tid; lr < nrows; lr += 256)
        offs[row0 + lr] = bb + rbase[lr] + rcnt[lr];
}

// ---------------------------------------------------------------------------
// bf16 gather core: half-wave scheme (slot=lane&31 covers d={2s,2s+1} both
// channels as uint2 = 8 B/lane; sub=lane>>5 interleaves edges). 4 edges per
// half-wave iteration. Pre-multiplied weights from edata4 (.z, .w).
// ---------------------------------------------------------------------------
__device__ __forceinline__ void edge_fma(const uint2 h, int wb0, int wb1, float4& acc) {
    float w0 = __int_as_float(wb0), w1 = __int_as_float(wb1);
    acc.x = fmaf(w0, bflo(h.x), acc.x);
    acc.y = fmaf(w1, bfhi(h.x), acc.y);
    acc.z = fmaf(w0, bflo(h.y), acc.z);
    acc.w = fmaf(w1, bfhi(h.y), acc.w);
}

__device__ __forceinline__ void row_gather16(const uint2* __restrict__ hp,
                                             const int4* __restrict__ edata4,
                                             int beg, int end, int slot, int sub,
                                             float4& acc) {
    int i = beg + sub;
    for (; i + 6 < end; i += 8) {                 // 4 edges per half-wave iter
        int4 e0 = edata4[i];
        int4 e1 = edata4[i + 2];
        int4 e2 = edata4[i + 4];
        int4 e3 = edata4[i + 6];
        uint2 h0 = hp[(size_t)((e0.x & 0x1FFFF) * 32 + slot)];
        uint2 h1 = hp[(size_t)((e1.x & 0x1FFFF) * 32 + slot)];
        uint2 h2 = hp[(size_t)((e2.x & 0x1FFFF) * 32 + slot)];
        uint2 h3 = hp[(size_t)((e3.x & 0x1FFFF) * 32 + slot)];
        edge_fma(h0, e0.z, e0.w, acc);
        edge_fma(h1, e1.z, e1.w, acc);
        edge_fma(h2, e2.z, e2.w, acc);
        edge_fma(h3, e3.z, e3.w, acc);
    }
    for (; i < end; i += 2) {
        int4 e = edata4[i];
        uint2 h = hp[(size_t)((e.x & 0x1FFFF) * 32 + slot)];
        edge_fma(h, e.z, e.w, acc);
    }
    acc.x += __shfl_xor(acc.x, 32);
    acc.y += __shfl_xor(acc.y, 32);
    acc.z += __shfl_xor(acc.z, 32);
    acc.w += __shfl_xor(acc.w, 32);
}

__device__ __forceinline__ int row_beg(const int* offs, int row) {
    return ((row & 511) == 0) ? (row >> 9) * BPAD : offs[row - 1];
}

// Layer 1: all N rows; bf16 in (Xp16), bf16 out (H116).
__global__ __launch_bounds__(256) void spmm_gather(const uint2* __restrict__ Hin16,
                                                   uint2* __restrict__ Hout16,
                                                   const int* __restrict__ offs,
                                                   const int4* __restrict__ edata4) {
    int lane = threadIdx.x & 63;
    int slot = lane & 31, sub = lane >> 5;
    int row  = (blockIdx.x * blockDim.x + threadIdx.x) >> 6;
    int beg = row_beg(offs, row);
    int end = offs[row];
    float4 acc = make_float4(0.f, 0.f, 0.f, 0.f);
    row_gather16(Hin16, edata4, beg, end, slot, sub, acc);
    if (sub == 0)
        Hout16[(size_t)row * 32 + slot] = make_uint2(packbf(acc.x, acc.y),
                                                     packbf(acc.z, acc.w));
}

// Layer 2: target rows only; bf16 in (H116), fp32 out (compact [M][64] float2).
__global__ __launch_bounds__(256) void spmm_gather_tgt(const uint2* __restrict__ Hin16,
                                                       float2* __restrict__ Hout,
                                                       const int* __restrict__ offs,
                                                       const int4* __restrict__ edata4,
                                                       const float* __restrict__ cw,
                                                       const int* __restrict__ tgt) {
    int lane = threadIdx.x & 63;
    int slot = lane & 31, sub = lane >> 5;
    int m    = (blockIdx.x * blockDim.x + threadIdx.x) >> 6;
    float f0[T_TYPES], f1[T_TYPES];
    load_filter(cw, 1, f0, f1);
    int row = tgt[m];
    int beg = row_beg(offs, row);
    int end = offs[row];
    float4 acc = make_float4(0.f, 0.f, 0.f, 0.f);
    for (int i = beg + sub; i < end; i += 2) {
        int4 e = edata4[i];
        int t = (e.x >> 17) & 3;
        float v = __int_as_float(e.y);
        uint2 h = Hin16[(size_t)((e.x & 0x1FFFF) * 32 + slot)];
        float w0 = v * f0[t], w1 = v * f1[t];
        acc.x = fmaf(w0, bflo(h.x), acc.x);
        acc.y = fmaf(w1, bfhi(h.x), acc.y);
        acc.z = fmaf(w0, bflo(h.y), acc.z);
        acc.w = fmaf(w1, bfhi(h.y), acc.w);
    }
    acc.x += __shfl_xor(acc.x, 32);
    acc.y += __shfl_xor(acc.y, 32);
    acc.z += __shfl_xor(acc.z, 32);
    acc.w += __shfl_xor(acc.w, 32);
    if (sub == 0)
        ((float4*)(Hout + (size_t)m * DD))[slot] = acc;
}

// ---------------------------------------------------------------------------
// Tail: 16 targets per block; X_ from bf16 plane, H2 from compact fp32 buffer.
// ---------------------------------------------------------------------------
__global__ __launch_bounds__(256) void tail_kernel(const unsigned* __restrict__ Xp16,
                                                   const float2* __restrict__ H2,
                                                   const float* __restrict__ lin1_w,
                                                   const float* __restrict__ lin1_b,
                                                   const float* __restrict__ lin_w,
                                                   const float* __restrict__ lin_b,
                                                   const int* __restrict__ tgt,
                                                   float* __restrict__ out) {
    __shared__ float l1w[W_INF * DD];        // 32 KB
    __shared__ float lw[DD * NUM_CLASS];     // 4 KB
    __shared__ float l1b[DD];
    __shared__ float lb[NUM_CLASS];
    __shared__ float hc[4][W_INF];
    __shared__ float hmid[4][DD];

    int tid = threadIdx.x;
    {
        const float4* g = (const float4*)lin1_w;
        float4* s = (float4*)l1w;
        #pragma unroll
        for (int i = 0; i < 8; ++i) s[tid + 256 * i] = g[tid + 256 * i];
        ((float4*)lw)[tid] = ((const float4*)lin_w)[tid];
        if (tid < DD) l1b[tid] = lin1_b[tid];
        else if (tid < DD + NUM_CLASS) lb[tid - DD] = lin_b[tid - DD];
    }
    __syncthreads();

    int w = tid >> 6, lane = tid & 63;

    #pragma unroll
    for (int g = 0; g < 4; ++g) {
        int m = blockIdx.x * 16 + g * 4 + w;      // M = 10000 = 625*16
        int n = tgt[m];
        unsigned xu = Xp16[(size_t)n * DD + lane];
        float2 h  = H2[(size_t)m * DD + lane];
        float a = BETA * bflo(xu) + (1.f - BETA) * h.x;
        float b = BETA * bfhi(xu) + (1.f - BETA) * h.y;
        hc[w][lane]      = fmaxf(a, 0.f);
        hc[w][DD + lane] = fmaxf(b, 0.f);
        __syncthreads();

        float acc = l1b[lane];
        #pragma unroll 8
        for (int k = 0; k < W_INF; ++k)
            acc = fmaf(hc[w][k], l1w[k * DD + lane], acc);
        hmid[w][lane] = acc;
        __syncthreads();

        if (lane < NUM_CLASS) {
            float o = lb[lane];
            #pragma unroll 8
            for (int k = 0; k < DD; ++k)
                o = fmaf(hmid[w][k], lw[k * NUM_CLASS + lane], o);
            out[(size_t)m * NUM_CLASS + lane] = o;
        }
        __syncthreads();
    }
}

// ---------------------------------------------------------------------------
extern "C" void kernel_launch(void* const* d_in, const int* in_sizes, int n_in,
                              void* d_out, int out_size, void* d_ws, size_t ws_size,
                              hipStream_t stream) {
    const float* X            = (const float*)d_in[0];
    const float* edge_value   = (const float*)d_in[1];
    const float* conv_weights = (const float*)d_in[2];
    const float* Ws           = (const float*)d_in[3];
    const float* lin1_w       = (const float*)d_in[4];
    const float* lin1_b       = (const float*)d_in[5];
    const float* lin_w        = (const float*)d_in[6];
    const float* lin_b        = (const float*)d_in[7];
    const int*   edge_index   = (const int*)d_in[8];
    const int*   target_x     = (const int*)d_in[9];
    float* out = (float*)d_out;

    float2*         B2   = (float2*)d_ws;                     // [M][64] float2 (5.12 MB)
    unsigned*       Xp16 = (unsigned*)(B2 + (size_t)M_TGT * DD);  // 25.6 MB
    unsigned*       H116 = Xp16 + PLANE2;                     // 25.6 MB
    unsigned short* Wsb  = (unsigned short*)(H116 + PLANE2);  // 32 KB
    int*            offs = (int*)(Wsb + C_CH * W_INF * DD);   // N ints
    int*            cursor = offs + N_NODES;                  // 256
    int4*           edata4 = (int4*)(cursor + 256);           // NBKT*BPAD int4 (28.9 MB)

    wsb_prep<<<64, 256, 0, stream>>>(Ws, Wsb);
    init_cursor<<<1, 256, 0, stream>>>(cursor);
    partition_kernel<<<NPART_BLK, 256, 0, stream>>>(edge_index, edge_value,
                                                    conv_weights, cursor, edata4);
    proj_mfma<<<(N_NODES + 63) / 64, 256, 0, stream>>>(X, Wsb, Xp16);
    rowsort_kernel<<<NBKT, 256, 0, stream>>>(cursor, edata4, offs);
    spmm_gather<<<(N_NODES * 64) / 256, 256, 0, stream>>>((const uint2*)Xp16,
                                                          (uint2*)H116, offs, edata4);
    spmm_gather_tgt<<<(M_TGT * 64) / 256, 256, 0, stream>>>((const uint2*)H116, B2,
                                                            offs, edata4,
                                                            conv_weights, target_x);
    tail_kernel<<<M_TGT / 16, 256, 0, stream>>>(Xp16, B2, lin1_w, lin1_b, lin_w, lin_b,
                                                target_x, out);
}

// Round 8
// 273.465 us; speedup vs baseline: 5.7689x; 1.0222x over previous
//
#include <hip/hip_runtime.h>

// ---- problem constants (from reference) ----
#define N_NODES   100000
#define T_TYPES   4
#define E_EDGES   400000
#define E4        100000                    // int4 groups per type-array
#define G_TOT     400000                    // total int4 groups = TE_TOT/4
#define TE_TOT    1600000
#define C_CH      2
#define L_LAYERS  2
#define W_INF     128
#define DD        64
#define NUM_CLASS 16
#define BETA      0.5f
#define M_TGT     10000

// CSR build tiling
#define NBKT      196                       // ceil(100000/512) buckets of 512 rows
#define BROWS     512
#define BPAD      9216                      // padded slots/bucket (mean 8163, sd 90 -> +11.7 sigma)
#define CHUNK_G   512                       // int4 groups per partition block (2048 edges)
#define NPART_BLK ((G_TOT + CHUNK_G - 1) / CHUNK_G)   // 782

// bf16 planes: u32 at [n*64 + d] = bf16(ch0) | bf16(ch1)<<16
// gather view: uint2 at [n*32 + slot] covers d = {2s, 2s+1}
static const size_t PLANE2 = (size_t)N_NODES * DD;    // u32 elements per plane

typedef __attribute__((ext_vector_type(8))) short short8x;   // 8 bf16 (4 VGPRs)
typedef __attribute__((ext_vector_type(4))) float f32x4;     // MFMA C/D

__device__ __forceinline__ unsigned bf16rne(float x) {   // RNE f32 -> bf16 bits
    unsigned u = __float_as_uint(x);
    return (u + 0x7FFFu + ((u >> 16) & 1u)) >> 16;
}
__device__ __forceinline__ unsigned packbf(float a, float b) {
    return bf16rne(a) | (bf16rne(b) << 16);
}
__device__ __forceinline__ float bflo(unsigned u) { return __uint_as_float(u << 16); }
__device__ __forceinline__ float bfhi(unsigned u) { return __uint_as_float(u & 0xFFFF0000u); }

// ---------------------------------------------------------------------------
// softmax filter for layer l, both channels
// ---------------------------------------------------------------------------
__device__ __forceinline__ void load_filter(const float* cw, int layer,
                                            float* f0, float* f1) {
    float m0 = -1e30f, m1 = -1e30f;
    #pragma unroll
    for (int t = 0; t < T_TYPES; ++t) {
        f0[t] = cw[layer * C_CH * T_TYPES + t];
        f1[t] = cw[layer * C_CH * T_TYPES + T_TYPES + t];
        m0 = fmaxf(m0, f0[t]); m1 = fmaxf(m1, f1[t]);
    }
    float s0 = 0.f, s1 = 0.f;
    #pragma unroll
    for (int t = 0; t < T_TYPES; ++t) {
        f0[t] = __expf(f0[t] - m0); s0 += f0[t];
        f1[t] = __expf(f1[t] - m1); s1 += f1[t];
    }
    #pragma unroll
    for (int t = 0; t < T_TYPES; ++t) { f0[t] /= s0; f1[t] /= s1; }
}

// ---------------------------------------------------------------------------
// prep: Wsb[c][d][k] = bf16(Ws[c][k][d]) (blocks 0..63) + cursor init (block 64)
// ---------------------------------------------------------------------------
__global__ void prep_kernel(const float* __restrict__ Ws,
                            unsigned short* __restrict__ Wsb,
                            int* __restrict__ cursor) {
    int b = blockIdx.x;
    int tid = threadIdx.x;
    if (b < 64) {
        int idx = b * 256 + tid;
        int c   = idx >> 13;
        int rem = idx & 8191;
        int d   = rem >> 7;
        int k   = rem & 127;
        Wsb[idx] = (unsigned short)bf16rne(Ws[c * (W_INF * DD) + k * DD + d]);
    } else {
        if (tid < NBKT) cursor[tid] = tid * BPAD;
    }
}

// ---------------------------------------------------------------------------
// MFMA projection: Xp16[n][d] = pack(bf16(X[n]·Ws[0][:,d]), bf16(X[n]·Ws[1][:,d]))
// ---------------------------------------------------------------------------
#define AROW 136   // LDS row pitch in shorts (128 + 8 pad)
__global__ __launch_bounds__(256) void proj_mfma(const float* __restrict__ X,
                                                 const unsigned short* __restrict__ Wsb,
                                                 unsigned* __restrict__ Xp16) {
    __shared__ unsigned short a_lds[64 * AROW];   // 17408 B
    int tid  = threadIdx.x;
    int row0 = blockIdx.x * 64;

    const float4* X4 = (const float4*)X;
    #pragma unroll
    for (int i = 0; i < 8; ++i) {
        int gi = tid + 256 * i;          // float4 index within tile (2048 total)
        int r  = gi >> 5;
        int c4 = gi & 31;
        int row = row0 + r;
        float4 v = make_float4(0.f, 0.f, 0.f, 0.f);
        if (row < N_NODES) v = X4[(size_t)row * 32 + c4];
        *(uint2*)&a_lds[r * AROW + c4 * 4] = make_uint2(packbf(v.x, v.y),
                                                        packbf(v.z, v.w));
    }
    __syncthreads();

    int wave = tid >> 6, lane = tid & 63;
    int m = lane & 15, q = lane >> 4;

    short8x A[4];
    #pragma unroll
    for (int ks = 0; ks < 4; ++ks)
        A[ks] = *(const short8x*)&a_lds[(wave * 16 + m) * AROW + ks * 32 + q * 8];

    #pragma unroll
    for (int ct = 0; ct < 4; ++ct) {
        f32x4 acc0 = {0.f, 0.f, 0.f, 0.f};
        f32x4 acc1 = {0.f, 0.f, 0.f, 0.f};
        #pragma unroll
        for (int ks = 0; ks < 4; ++ks) {
            short8x B0 = *(const short8x*)(Wsb + (ct * 16 + m) * 128 + ks * 32 + q * 8);
            short8x B1 = *(const short8x*)(Wsb + 8192 + (ct * 16 + m) * 128 + ks * 32 + q * 8);
            acc0 = __builtin_amdgcn_mfma_f32_16x16x32_bf16(A[ks], B0, acc0, 0, 0, 0);
            acc1 = __builtin_amdgcn_mfma_f32_16x16x32_bf16(A[ks], B1, acc1, 0, 0, 0);
        }
        #pragma unroll
        for (int r = 0; r < 4; ++r) {
            int row = row0 + wave * 16 + q * 4 + r;
            if (row < N_NODES)
                Xp16[(size_t)row * DD + ct * 16 + m] = packbf(acc0[r], acc1[r]);
        }
    }
}

// ---------------------------------------------------------------------------
// Partition edges into bucket-padded 8B records:
//   edata2[pos] = { col | t<<17 | (row&511)<<19 ,
//                   packbf(val*f0_l1[t], val*f1_l1[t]) }
// ---------------------------------------------------------------------------
__global__ __launch_bounds__(256) void partition_kernel(const int* __restrict__ edge_index,
                                                        const float* __restrict__ edge_value,
                                                        const float* __restrict__ cw,
                                                        int* __restrict__ cursor,
                                                        int2* __restrict__ edata2) {
    __shared__ int cnt[NBKT];
    __shared__ int lbase[NBKT];
    __shared__ int gbase[NBKT];
    __shared__ int2 le[CHUNK_G * 4];              // 16 KB
    __shared__ unsigned char lbk[CHUNK_G * 4];    // 2 KB
    int tid = threadIdx.x;
    if (tid < NBKT) cnt[tid] = 0;
    __syncthreads();

    float f0[T_TYPES], f1[T_TYPES];
    load_filter(cw, 0, f0, f1);

    int px[8], pv[8], rk[8], bk[8];
    int ne = 0;
    #pragma unroll
    for (int g = 0; g < 2; ++g) {
        int idx = blockIdx.x * CHUNK_G + g * 256 + tid;
        if (idx < G_TOT) {
            int t = idx / E4, r = idx - t * E4;
            const int* bptr = edge_index + (size_t)t * 2 * E_EDGES;
            int4   rw = ((const int4*)bptr)[r];
            int4   cl = ((const int4*)(bptr + E_EDGES))[r];
            float4 vv = ((const float4*)(edge_value + (size_t)t * E_EDGES))[r];
            int tb = t << 17;
            int   rr[4] = {rw.x, rw.y, rw.z, rw.w};
            int   cc[4] = {cl.x, cl.y, cl.z, cl.w};
            float vf[4] = {vv.x, vv.y, vv.z, vv.w};
            #pragma unroll
            for (int k = 0; k < 4; ++k) {
                int b = rr[k] >> 9;
                px[ne] = cc[k] | tb | ((rr[k] & 511) << 19);
                pv[ne] = __float_as_int(vf[k]);
                bk[ne] = b;
                rk[ne] = atomicAdd(&cnt[b], 1);
                ++ne;
            }
        }
    }
    __syncthreads();
    if (tid < 64) {                                // scan cnt -> lbase
        int c[4]; int s = 0;
        #pragma unroll
        for (int k = 0; k < 4; ++k) {
            int idx = tid * 4 + k;
            c[k] = (idx < NBKT) ? cnt[idx] : 0;
            s += c[k];
        }
        int inc = s;
        #pragma unroll
        for (int off = 1; off < 64; off <<= 1) {
            int v = __shfl_up(inc, off);
            if (tid >= off) inc += v;
        }
        int base = inc - s;
        #pragma unroll
        for (int k = 0; k < 4; ++k) {
            int idx = tid * 4 + k;
            if (idx < NBKT) lbase[idx] = base;
            base += c[k];
        }
    }
    __syncthreads();
    #pragma unroll
    for (int k = 0; k < 8; ++k) {
        if (k < ne) {
            int slot = lbase[bk[k]] + rk[k];
            le[slot]  = make_int2(px[k], pv[k]);
            lbk[slot] = (unsigned char)bk[k];
        }
    }
    __syncthreads();
    if (tid < NBKT) gbase[tid] = cnt[tid] ? atomicAdd(&cursor[tid], cnt[tid]) : 0;
    __syncthreads();
    int ngrp = min(CHUNK_G, G_TOT - blockIdx.x * CHUNK_G);
    int nloc = 4 * ngrp;
    for (int j = tid; j < nloc; j += 256) {
        int b = lbk[j];
        int2 e = le[j];
        int t = (e.x >> 17) & 3;
        float v = __int_as_float(e.y);
        edata2[gbase[b] + (j - lbase[b])] =
            make_int2(e.x, (int)packbf(v * f0[t], v * f1[t]));
    }
}

// ---------------------------------------------------------------------------
// Per-bucket in-LDS row-sort of the padded edata2 segment (in place)
// + per-row end offsets. 80 KB LDS, 1024 threads, 196 blocks.
// ---------------------------------------------------------------------------
__global__ __launch_bounds__(1024) void rowsort_kernel(const int* __restrict__ cursor,
                                                       int2* __restrict__ edata2,
                                                       int* __restrict__ offs) {
    __shared__ int rcnt[BROWS];
    __shared__ int rbase[BROWS];
    __shared__ int rcur[BROWS];
    __shared__ int2 le[BPAD];                     // 73728 B
    int b   = blockIdx.x;
    int tid = threadIdx.x;
    int bb  = b * BPAD;
    int cnt = cursor[b] - bb;
    if (tid < BROWS) rcnt[tid] = 0;
    __syncthreads();
    for (int j = tid; j < cnt; j += 1024) {
        int2 e = edata2[bb + j];
        le[j] = e;
        atomicAdd(&rcnt[(e.x >> 19) & 511], 1);
    }
    __syncthreads();
    if (tid < 64) {                                // scan 512 row counts
        int c[8]; int s = 0;
        #pragma unroll
        for (int k = 0; k < 8; ++k) { c[k] = rcnt[tid * 8 + k]; s += c[k]; }
        int inc = s;
        #pragma unroll
        for (int off = 1; off < 64; off <<= 1) {
            int v = __shfl_up(inc, off);
            if (tid >= off) inc += v;
        }
        int base = inc - s;
        #pragma unroll
        for (int k = 0; k < 8; ++k) { rbase[tid * 8 + k] = base; base += c[k]; }
    }
    __syncthreads();
    if (tid < BROWS) rcur[tid] = rbase[tid];
    __syncthreads();
    for (int j = tid; j < cnt; j += 1024) {
        int2 e = le[j];
        int lr = (e.x >> 19) & 511;
        int pos = atomicAdd(&rcur[lr], 1);
        edata2[bb + pos] = e;
    }
    int row0  = b * BROWS;
    int nrows = min(BROWS, N_NODES - row0);
    if (tid < nrows)
        offs[row0 + tid] = bb + rbase[tid] + rcnt[tid];
}

// ---------------------------------------------------------------------------
// bf16 gather core: half-wave scheme (slot=lane&31 covers d={2s,2s+1} both
// channels as uint2 = 8 B/lane; sub=lane>>5 interleaves edges).
// Premultiplied bf16 weight pair in e.y.
// ---------------------------------------------------------------------------
__device__ __forceinline__ void edge_fma(const uint2 h, unsigned wp, float4& acc) {
    float w0 = bflo(wp), w1 = bfhi(wp);
    acc.x = fmaf(w0, bflo(h.x), acc.x);
    acc.y = fmaf(w1, bfhi(h.x), acc.y);
    acc.z = fmaf(w0, bflo(h.y), acc.z);
    acc.w = fmaf(w1, bfhi(h.y), acc.w);
}

__device__ __forceinline__ int row_beg(const int* offs, int row) {
    return ((row & 511) == 0) ? (row >> 9) * BPAD : offs[row - 1];
}

// Layer 1: all N rows; bf16 in (Xp16), bf16 out (H116).
__global__ __launch_bounds__(256) void spmm_gather(const uint2* __restrict__ Hin16,
                                                   uint2* __restrict__ Hout16,
                                                   const int* __restrict__ offs,
                                                   const int2* __restrict__ edata2) {
    int lane = threadIdx.x & 63;
    int slot = lane & 31, sub = lane >> 5;
    int row  = (blockIdx.x * blockDim.x + threadIdx.x) >> 6;
    int beg = row_beg(offs, row);
    int end = offs[row];
    float4 acc = make_float4(0.f, 0.f, 0.f, 0.f);
    int i = beg + sub;
    for (; i + 6 < end; i += 8) {                 // 4 edges per half-wave iter
        int2 e0 = edata2[i];
        int2 e1 = edata2[i + 2];
        int2 e2 = edata2[i + 4];
        int2 e3 = edata2[i + 6];
        uint2 h0 = Hin16[(size_t)((e0.x & 0x1FFFF) * 32 + slot)];
        uint2 h1 = Hin16[(size_t)((e1.x & 0x1FFFF) * 32 + slot)];
        uint2 h2 = Hin16[(size_t)((e2.x & 0x1FFFF) * 32 + slot)];
        uint2 h3 = Hin16[(size_t)((e3.x & 0x1FFFF) * 32 + slot)];
        edge_fma(h0, (unsigned)e0.y, acc);
        edge_fma(h1, (unsigned)e1.y, acc);
        edge_fma(h2, (unsigned)e2.y, acc);
        edge_fma(h3, (unsigned)e3.y, acc);
    }
    for (; i < end; i += 2) {
        int2 e = edata2[i];
        uint2 h = Hin16[(size_t)((e.x & 0x1FFFF) * 32 + slot)];
        edge_fma(h, (unsigned)e.y, acc);
    }
    acc.x += __shfl_xor(acc.x, 32);
    acc.y += __shfl_xor(acc.y, 32);
    acc.z += __shfl_xor(acc.z, 32);
    acc.w += __shfl_xor(acc.w, 32);
    if (sub == 0)
        Hout16[(size_t)row * 32 + slot] = make_uint2(packbf(acc.x, acc.y),
                                                     packbf(acc.z, acc.w));
}

// ---------------------------------------------------------------------------
// Fused layer-2 gather (target rows) + tail MLP. Block = 4 waves = 4 targets.
// Layer-2 edge weights = stored_l1_weight * (f_l2[t]/f_l1[t]).
// ---------------------------------------------------------------------------
__global__ __launch_bounds__(256) void tgt_tail_kernel(const uint2* __restrict__ Hin16,
                                                       const unsigned* __restrict__ Xp16,
                                                       const int* __restrict__ offs,
                                                       const int2* __restrict__ edata2,
                                                       const float* __restrict__ cw,
                                                       const int* __restrict__ tgt,
                                                       const float* __restrict__ lin1_w,
                                                       const float* __restrict__ lin1_b,
                                                       const float* __restrict__ lin_w,
                                                       const float* __restrict__ lin_b,
                                                       float* __restrict__ out) {
    __shared__ float l1w[W_INF * DD];        // 32 KB
    __shared__ float lw[DD * NUM_CLASS];     // 4 KB
    __shared__ float l1b[DD];
    __shared__ float lb[NUM_CLASS];
    __shared__ float hc[4][W_INF];
    __shared__ float hmid[4][DD];

    int tid = threadIdx.x;
    {
        const float4* g = (const float4*)lin1_w;
        float4* s = (float4*)l1w;
        #pragma unroll
        for (int i = 0; i < 8; ++i) s[tid + 256 * i] = g[tid + 256 * i];
        ((float4*)lw)[tid] = ((const float4*)lin_w)[tid];
        if (tid < DD) l1b[tid] = lin1_b[tid];
        else if (tid < DD + NUM_CLASS) lb[tid - DD] = lin_b[tid - DD];
    }

    // layer-2 weight ratio tables
    float f0a[T_TYPES], f1a[T_TYPES], f0b[T_TYPES], f1b[T_TYPES];
    load_filter(cw, 0, f0a, f1a);
    load_filter(cw, 1, f0b, f1b);
    float r0[T_TYPES], r1[T_TYPES];
    #pragma unroll
    for (int t = 0; t < T_TYPES; ++t) { r0[t] = f0b[t] / f0a[t]; r1[t] = f1b[t] / f1a[t]; }

    int w = tid >> 6, lane = tid & 63;
    int slot = lane & 31, sub = lane >> 5;
    int m = blockIdx.x * 4 + w;               // M = 10000 = 2500*4
    int row = tgt[m];
    int beg = row_beg(offs, row);
    int end = offs[row];
    float4 acc = make_float4(0.f, 0.f, 0.f, 0.f);
    for (int i = beg + sub; i < end; i += 2) {
        int2 e = edata2[i];
        int t = (e.x >> 17) & 3;
        uint2 h = Hin16[(size_t)((e.x & 0x1FFFF) * 32 + slot)];
        unsigned wp = (unsigned)e.y;
        float w0 = bflo(wp) * r0[t], w1 = bfhi(wp) * r1[t];
        acc.x = fmaf(w0, bflo(h.x), acc.x);
        acc.y = fmaf(w1, bfhi(h.x), acc.y);
        acc.z = fmaf(w0, bflo(h.y), acc.z);
        acc.w = fmaf(w1, bfhi(h.y), acc.w);
    }
    acc.x += __shfl_xor(acc.x, 32);
    acc.y += __shfl_xor(acc.y, 32);
    acc.z += __shfl_xor(acc.z, 32);
    acc.w += __shfl_xor(acc.w, 32);

    if (sub == 0) {
        uint2 xu = ((const uint2*)Xp16)[(size_t)row * 32 + slot];
        int d0 = 2 * slot, d1 = 2 * slot + 1;
        hc[w][d0]      = fmaxf(BETA * bflo(xu.x) + (1.f - BETA) * acc.x, 0.f);
        hc[w][DD + d0] = fmaxf(BETA * bfhi(xu.x) + (1.f - BETA) * acc.y, 0.f);
        hc[w][d1]      = fmaxf(BETA * bflo(xu.y) + (1.f - BETA) * acc.z, 0.f);
        hc[w][DD + d1] = fmaxf(BETA * bfhi(xu.y) + (1.f - BETA) * acc.w, 0.f);
    }
    __syncthreads();

    float a1 = l1b[lane];
    #pragma unroll 8
    for (int k = 0; k < W_INF; ++k)
        a1 = fmaf(hc[w][k], l1w[k * DD + lane], a1);
    hmid[w][lane] = a1;
    __syncthreads();

    if (lane < NUM_CLASS) {
        float o = lb[lane];
        #pragma unroll 8
        for (int k = 0; k < DD; ++k)
            o = fmaf(hmid[w][k], lw[k * NUM_CLASS + lane], o);
        out[(size_t)m * NUM_CLASS + lane] = o;
    }
}

// ---------------------------------------------------------------------------
extern "C" void kernel_launch(void* const* d_in, const int* in_sizes, int n_in,
                              void* d_out, int out_size, void* d_ws, size_t ws_size,
                              hipStream_t stream) {
    const float* X            = (const float*)d_in[0];
    const float* edge_value   = (const float*)d_in[1];
    const float* conv_weights = (const float*)d_in[2];
    const float* Ws           = (const float*)d_in[3];
    const float* lin1_w       = (const float*)d_in[4];
    const float* lin1_b       = (const float*)d_in[5];
    const float* lin_w        = (const float*)d_in[6];
    const float* lin_b        = (const float*)d_in[7];
    const int*   edge_index   = (const int*)d_in[8];
    const int*   target_x     = (const int*)d_in[9];
    float* out = (float*)d_out;

    unsigned*       Xp16 = (unsigned*)d_ws;                   // 25.6 MB
    unsigned*       H116 = Xp16 + PLANE2;                     // 25.6 MB
    unsigned short* Wsb  = (unsigned short*)(H116 + PLANE2);  // 32 KB
    int*            offs = (int*)(Wsb + C_CH * W_INF * DD);   // N ints
    int*            cursor = offs + N_NODES;                  // 256
    int2*           edata2 = (int2*)(cursor + 256);           // NBKT*BPAD int2 (14.5 MB)

    prep_kernel<<<65, 256, 0, stream>>>(Ws, Wsb, cursor);
    partition_kernel<<<NPART_BLK, 256, 0, stream>>>(edge_index, edge_value,
                                                    conv_weights, cursor, edata2);
    proj_mfma<<<(N_NODES + 63) / 64, 256, 0, stream>>>(X, Wsb, Xp16);
    rowsort_kernel<<<NBKT, 1024, 0, stream>>>(cursor, edata2, offs);
    spmm_gather<<<(N_NODES * 64) / 256, 256, 0, stream>>>((const uint2*)Xp16,
                                                          (uint2*)H116, offs, edata2);
    tgt_tail_kernel<<<M_TGT / 4, 256, 0, stream>>>((const uint2*)H116, Xp16, offs,
                                                   edata2, conv_weights, target_x,
                                                   lin1_w, lin1_b, lin_w, lin_b, out);
}

// Round 9
// 253.046 us; speedup vs baseline: 6.2344x; 1.0807x over previous
//
#include <hip/hip_runtime.h>

// ---- problem constants (from reference) ----
#define N_NODES   100000
#define T_TYPES   4
#define E_EDGES   400000
#define E4        100000                    // int4 groups per type-array
#define G_TOT     400000                    // total int4 groups = TE_TOT/4
#define TE_TOT    1600000
#define C_CH      2
#define L_LAYERS  2
#define W_INF     128
#define DD        64
#define NUM_CLASS 16
#define BETA      0.5f
#define M_TGT     10000

// CSR build tiling
#define NBKT      391                       // ceil(100000/256) buckets of 256 rows
#define BROWS     256
#define BPAD      4864                      // slots/bucket (mean 4096, sd 64 -> +12 sigma)
#define CHUNK_G   1024                      // int4 groups per partition block (4096 edges)
#define NPART_BLK 391                       // ceil(400000/1024)
#define PROJ_BLK  1563                      // ceil(100000/64)

// bf16 planes: u32 at [n*64 + d] = bf16(ch0) | bf16(ch1)<<16
static const size_t PLANE2 = (size_t)N_NODES * DD;    // u32 elements per plane

typedef __attribute__((ext_vector_type(8))) short short8x;   // 8 bf16 (4 VGPRs)
typedef __attribute__((ext_vector_type(4))) float f32x4;     // MFMA C/D

__device__ __forceinline__ unsigned bf16rne(float x) {   // RNE f32 -> bf16 bits
    unsigned u = __float_as_uint(x);
    return (u + 0x7FFFu + ((u >> 16) & 1u)) >> 16;
}
__device__ __forceinline__ unsigned packbf(float a, float b) {
    return bf16rne(a) | (bf16rne(b) << 16);
}
__device__ __forceinline__ float bflo(unsigned u) { return __uint_as_float(u << 16); }
__device__ __forceinline__ float bfhi(unsigned u) { return __uint_as_float(u & 0xFFFF0000u); }

__device__ __forceinline__ void load_filter(const float* cw, int layer,
                                            float* f0, float* f1) {
    float m0 = -1e30f, m1 = -1e30f;
    #pragma unroll
    for (int t = 0; t < T_TYPES; ++t) {
        f0[t] = cw[layer * C_CH * T_TYPES + t];
        f1[t] = cw[layer * C_CH * T_TYPES + T_TYPES + t];
        m0 = fmaxf(m0, f0[t]); m1 = fmaxf(m1, f1[t]);
    }
    float s0 = 0.f, s1 = 0.f;
    #pragma unroll
    for (int t = 0; t < T_TYPES; ++t) {
        f0[t] = __expf(f0[t] - m0); s0 += f0[t];
        f1[t] = __expf(f1[t] - m1); s1 += f1[t];
    }
    #pragma unroll
    for (int t = 0; t < T_TYPES; ++t) { f0[t] /= s0; f1[t] /= s1; }
}

// ---------------------------------------------------------------------------
// prep: Wsb[c][d][k] = bf16(Ws[c][k][d]) (blocks 0..63) + cursor init (64..65)
// ---------------------------------------------------------------------------
__global__ void prep_kernel(const float* __restrict__ Ws,
                            unsigned short* __restrict__ Wsb,
                            int* __restrict__ cursor) {
    int b = blockIdx.x;
    int tid = threadIdx.x;
    if (b < 64) {
        int idx = b * 256 + tid;
        int c   = idx >> 13;
        int rem = idx & 8191;
        int d   = rem >> 7;
        int k   = rem & 127;
        Wsb[idx] = (unsigned short)bf16rne(Ws[c * (W_INF * DD) + k * DD + d]);
    } else {
        int idx = (b - 64) * 256 + tid;
        if (idx < NBKT) cursor[idx] = idx * BPAD;
    }
}

// ---------------------------------------------------------------------------
// Fused: blocks [0, NPART_BLK) run edge partition; [NPART_BLK, +PROJ_BLK)
// run the MFMA projection. Independent work; LDS union.
// partition record: edata2[pos] = { col | t<<17 | (row&255)<<19 ,
//                                   packbf(val*f0_l1[t], val*f1_l1[t]) }
// ---------------------------------------------------------------------------
#define AROW 136   // proj LDS row pitch in shorts (128 + 8 pad)
#define SMEM_BYTES 45664

__global__ __launch_bounds__(256) void build_proj_kernel(
        const int* __restrict__ edge_index,
        const float* __restrict__ edge_value,
        const float* __restrict__ cw,
        int* __restrict__ cursor,
        int2* __restrict__ edata2,
        const float* __restrict__ X,
        const unsigned short* __restrict__ Wsb,
        unsigned* __restrict__ Xp16) {
    __shared__ __align__(16) char smem[SMEM_BYTES];
    int tid = threadIdx.x;

    if (blockIdx.x < NPART_BLK) {
        // ---------------- partition ----------------
        int* cnt   = (int*)smem;                         // 391 (pad to 392)
        int* lbase = cnt + 392;
        int* gbase = lbase + 392;
        int2* le   = (int2*)(smem + 4704);               // 4096 * 8 = 32768
        unsigned short* lbk = (unsigned short*)(smem + 4704 + 32768); // 4096*2

        int p = blockIdx.x;
        for (int j = tid; j < NBKT; j += 256) cnt[j] = 0;
        __syncthreads();

        float f0[T_TYPES], f1[T_TYPES];
        load_filter(cw, 0, f0, f1);

        int px[16], pv[16], rk[16], bk[16];
        int ne = 0;
        #pragma unroll
        for (int g = 0; g < 4; ++g) {
            int idx = p * CHUNK_G + g * 256 + tid;
            if (idx < G_TOT) {
                int t = idx / E4, r = idx - t * E4;
                const int* bptr = edge_index + (size_t)t * 2 * E_EDGES;
                int4   rw = ((const int4*)bptr)[r];
                int4   cl = ((const int4*)(bptr + E_EDGES))[r];
                float4 vv = ((const float4*)(edge_value + (size_t)t * E_EDGES))[r];
                int tb = t << 17;
                int   rr[4] = {rw.x, rw.y, rw.z, rw.w};
                int   cc[4] = {cl.x, cl.y, cl.z, cl.w};
                float vf[4] = {vv.x, vv.y, vv.z, vv.w};
                #pragma unroll
                for (int k = 0; k < 4; ++k) {
                    int b = rr[k] >> 8;
                    px[ne] = cc[k] | tb | ((rr[k] & 255) << 19);
                    pv[ne] = __float_as_int(vf[k]);
                    bk[ne] = b;
                    rk[ne] = atomicAdd(&cnt[b], 1);
                    ++ne;
                }
            }
        }
        __syncthreads();
        if (tid < 64) {                                // scan cnt -> lbase (7/lane)
            int c[7]; int s = 0;
            #pragma unroll
            for (int k = 0; k < 7; ++k) {
                int idx = tid * 7 + k;
                c[k] = (idx < NBKT) ? cnt[idx] : 0;
                s += c[k];
            }
            int inc = s;
            #pragma unroll
            for (int off = 1; off < 64; off <<= 1) {
                int v = __shfl_up(inc, off);
                if (tid >= off) inc += v;
            }
            int base = inc - s;
            #pragma unroll
            for (int k = 0; k < 7; ++k) {
                int idx = tid * 7 + k;
                if (idx < NBKT) lbase[idx] = base;
                base += c[k];
            }
        }
        __syncthreads();
        #pragma unroll
        for (int k = 0; k < 16; ++k) {
            if (k < ne) {
                int slot = lbase[bk[k]] + rk[k];
                le[slot]  = make_int2(px[k], pv[k]);
                lbk[slot] = (unsigned short)bk[k];
            }
        }
        __syncthreads();
        for (int j = tid; j < NBKT; j += 256)
            gbase[j] = cnt[j] ? atomicAdd(&cursor[j], cnt[j]) : 0;
        __syncthreads();
        int ngrp = min(CHUNK_G, G_TOT - p * CHUNK_G);
        int nloc = 4 * ngrp;
        for (int j = tid; j < nloc; j += 256) {
            int b = lbk[j];
            int2 e = le[j];
            int t = (e.x >> 17) & 3;
            float v = __int_as_float(e.y);
            edata2[gbase[b] + (j - lbase[b])] =
                make_int2(e.x, (int)packbf(v * f0[t], v * f1[t]));
        }
    } else {
        // ---------------- MFMA projection ----------------
        unsigned short* a_lds = (unsigned short*)smem;    // 64*AROW*2 = 17408
        int row0 = (blockIdx.x - NPART_BLK) * 64;

        const float4* X4 = (const float4*)X;
        #pragma unroll
        for (int i = 0; i < 8; ++i) {
            int gi = tid + 256 * i;          // float4 index within tile
            int r  = gi >> 5;
            int c4 = gi & 31;
            int row = row0 + r;
            float4 v = make_float4(0.f, 0.f, 0.f, 0.f);
            if (row < N_NODES) v = X4[(size_t)row * 32 + c4];
            *(uint2*)&a_lds[r * AROW + c4 * 4] = make_uint2(packbf(v.x, v.y),
                                                            packbf(v.z, v.w));
        }
        __syncthreads();

        int wave = tid >> 6, lane = tid & 63;
        int m = lane & 15, q = lane >> 4;

        short8x A[4];
        #pragma unroll
        for (int ks = 0; ks < 4; ++ks)
            A[ks] = *(const short8x*)&a_lds[(wave * 16 + m) * AROW + ks * 32 + q * 8];

        #pragma unroll
        for (int ct = 0; ct < 4; ++ct) {
            f32x4 acc0 = {0.f, 0.f, 0.f, 0.f};
            f32x4 acc1 = {0.f, 0.f, 0.f, 0.f};
            #pragma unroll
            for (int ks = 0; ks < 4; ++ks) {
                short8x B0 = *(const short8x*)(Wsb + (ct * 16 + m) * 128 + ks * 32 + q * 8);
                short8x B1 = *(const short8x*)(Wsb + 8192 + (ct * 16 + m) * 128 + ks * 32 + q * 8);
                acc0 = __builtin_amdgcn_mfma_f32_16x16x32_bf16(A[ks], B0, acc0, 0, 0, 0);
                acc1 = __builtin_amdgcn_mfma_f32_16x16x32_bf16(A[ks], B1, acc1, 0, 0, 0);
            }
            #pragma unroll
            for (int r = 0; r < 4; ++r) {
                int row = row0 + wave * 16 + q * 4 + r;
                if (row < N_NODES)
                    Xp16[(size_t)row * DD + ct * 16 + m] = packbf(acc0[r], acc1[r]);
            }
        }
    }
}

// ---------------------------------------------------------------------------
// Per-bucket in-LDS row-sort (256 rows/bucket) + per-row end offsets.
// 42 KB LDS, 512 threads, 391 blocks.
// ---------------------------------------------------------------------------
__global__ __launch_bounds__(512) void rowsort_kernel(const int* __restrict__ cursor,
                                                      int2* __restrict__ edata2,
                                                      int* __restrict__ offs) {
    __shared__ int rcnt[BROWS];
    __shared__ int rbase[BROWS];
    __shared__ int rcur[BROWS];
    __shared__ int2 le[BPAD];                     // 38912 B
    int b   = blockIdx.x;
    int tid = threadIdx.x;
    int bb  = b * BPAD;
    int cnt = cursor[b] - bb;
    if (tid < BROWS) rcnt[tid] = 0;
    __syncthreads();
    for (int j = tid; j < cnt; j += 512) {
        int2 e = edata2[bb + j];
        le[j] = e;
        atomicAdd(&rcnt[(e.x >> 19) & 255], 1);
    }
    __syncthreads();
    if (tid < 64) {                                // scan 256 row counts
        int c[4]; int s = 0;
        #pragma unroll
        for (int k = 0; k < 4; ++k) { c[k] = rcnt[tid * 4 + k]; s += c[k]; }
        int inc = s;
        #pragma unroll
        for (int off = 1; off < 64; off <<= 1) {
            int v = __shfl_up(inc, off);
            if (tid >= off) inc += v;
        }
        int base = inc - s;
        #pragma unroll
        for (int k = 0; k < 4; ++k) { rbase[tid * 4 + k] = base; base += c[k]; }
    }
    __syncthreads();
    if (tid < BROWS) rcur[tid] = rbase[tid];
    __syncthreads();
    for (int j = tid; j < cnt; j += 512) {
        int2 e = le[j];
        int lr = (e.x >> 19) & 255;
        int pos = atomicAdd(&rcur[lr], 1);
        edata2[bb + pos] = e;
    }
    int row0  = b * BROWS;
    int nrows = min(BROWS, N_NODES - row0);
    if (tid < nrows)
        offs[row0 + tid] = bb + rbase[tid] + rcnt[tid];
}

// ---------------------------------------------------------------------------
// Quarter-wave bf16 gather: s16 = lane&15 covers d = {4s..4s+3} both channels
// as uint4 = 16 B/lane; sub = lane>>4 interleaves 4 edges per wave.
// One gather VMEM instruction serves 4 edges (1024 B). Unroll 2.
// ---------------------------------------------------------------------------
__device__ __forceinline__ void qfma(const uint4 h, unsigned wp,
                                     float4& a, float4& b) {
    float w0 = bflo(wp), w1 = bfhi(wp);
    a.x = fmaf(w0, bflo(h.x), a.x);
    a.y = fmaf(w1, bfhi(h.x), a.y);
    a.z = fmaf(w0, bflo(h.y), a.z);
    a.w = fmaf(w1, bfhi(h.y), a.w);
    b.x = fmaf(w0, bflo(h.z), b.x);
    b.y = fmaf(w1, bfhi(h.z), b.y);
    b.z = fmaf(w0, bflo(h.w), b.z);
    b.w = fmaf(w1, bfhi(h.w), b.w);
}

__device__ __forceinline__ void qreduce(float4& a, float4& b) {
    a.x += __shfl_xor(a.x, 16); a.y += __shfl_xor(a.y, 16);
    a.z += __shfl_xor(a.z, 16); a.w += __shfl_xor(a.w, 16);
    b.x += __shfl_xor(b.x, 16); b.y += __shfl_xor(b.y, 16);
    b.z += __shfl_xor(b.z, 16); b.w += __shfl_xor(b.w, 16);
    a.x += __shfl_xor(a.x, 32); a.y += __shfl_xor(a.y, 32);
    a.z += __shfl_xor(a.z, 32); a.w += __shfl_xor(a.w, 32);
    b.x += __shfl_xor(b.x, 32); b.y += __shfl_xor(b.y, 32);
    b.z += __shfl_xor(b.z, 32); b.w += __shfl_xor(b.w, 32);
}

__device__ __forceinline__ int row_beg(const int* offs, int row) {
    return ((row & 255) == 0) ? (row >> 8) * BPAD : offs[row - 1];
}

// Layer 1: all N rows; bf16 in (Xp16), bf16 out (H116).
__global__ __launch_bounds__(256) void spmm_gather(const unsigned* __restrict__ Hin16,
                                                   unsigned* __restrict__ Hout16,
                                                   const int* __restrict__ offs,
                                                   const int2* __restrict__ edata2) {
    int lane = threadIdx.x & 63;
    int s16 = lane & 15, sub = lane >> 4;
    int row  = (blockIdx.x * blockDim.x + threadIdx.x) >> 6;
    int beg = row_beg(offs, row);
    int end = offs[row];
    const uint4* hp = (const uint4*)Hin16;
    float4 a = make_float4(0.f, 0.f, 0.f, 0.f);
    float4 b = make_float4(0.f, 0.f, 0.f, 0.f);
    int i = beg + sub;
    for (; i + 4 < end; i += 8) {                 // 2 edges per quarter per iter
        int2 e0 = edata2[i];
        int2 e1 = edata2[i + 4];
        uint4 h0 = hp[(size_t)(e0.x & 0x1FFFF) * 16 + s16];
        uint4 h1 = hp[(size_t)(e1.x & 0x1FFFF) * 16 + s16];
        qfma(h0, (unsigned)e0.y, a, b);
        qfma(h1, (unsigned)e1.y, a, b);
    }
    if (i < end) {
        int2 e = edata2[i];
        uint4 h = hp[(size_t)(e.x & 0x1FFFF) * 16 + s16];
        qfma(h, (unsigned)e.y, a, b);
    }
    qreduce(a, b);
    if (sub == 0)
        ((uint4*)Hout16)[(size_t)row * 16 + s16] =
            make_uint4(packbf(a.x, a.y), packbf(a.z, a.w),
                       packbf(b.x, b.y), packbf(b.z, b.w));
}

// ---------------------------------------------------------------------------
// Fused layer-2 gather (target rows) + tail MLP. Block = 4 waves = 4 targets.
// Layer-2 edge weights = stored_l1_weight * (f_l2[t]/f_l1[t]).
// ---------------------------------------------------------------------------
__global__ __launch_bounds__(256) void tgt_tail_kernel(const unsigned* __restrict__ Hin16,
                                                       const unsigned* __restrict__ Xp16,
                                                       const int* __restrict__ offs,
                                                       const int2* __restrict__ edata2,
                                                       const float* __restrict__ cw,
                                                       const int* __restrict__ tgt,
                                                       const float* __restrict__ lin1_w,
                                                       const float* __restrict__ lin1_b,
                                                       const float* __restrict__ lin_w,
                                                       const float* __restrict__ lin_b,
                                                       float* __restrict__ out) {
    __shared__ float l1w[W_INF * DD];        // 32 KB
    __shared__ float lw[DD * NUM_CLASS];     // 4 KB
    __shared__ float l1b[DD];
    __shared__ float lb[NUM_CLASS];
    __shared__ float hc[4][W_INF];
    __shared__ float hmid[4][DD];

    int tid = threadIdx.x;
    {
        const float4* g = (const float4*)lin1_w;
        float4* s = (float4*)l1w;
        #pragma unroll
        for (int i = 0; i < 8; ++i) s[tid + 256 * i] = g[tid + 256 * i];
        ((float4*)lw)[tid] = ((const float4*)lin_w)[tid];
        if (tid < DD) l1b[tid] = lin1_b[tid];
        else if (tid < DD + NUM_CLASS) lb[tid - DD] = lin_b[tid - DD];
    }

    float f0a[T_TYPES], f1a[T_TYPES], f0b[T_TYPES], f1b[T_TYPES];
    load_filter(cw, 0, f0a, f1a);
    load_filter(cw, 1, f0b, f1b);
    float r0[T_TYPES], r1[T_TYPES];
    #pragma unroll
    for (int t = 0; t < T_TYPES; ++t) { r0[t] = f0b[t] / f0a[t]; r1[t] = f1b[t] / f1a[t]; }

    int w = tid >> 6, lane = tid & 63;
    int s16 = lane & 15, sub = lane >> 4;
    int m = blockIdx.x * 4 + w;               // M = 10000 = 2500*4
    int row = tgt[m];
    int beg = row_beg(offs, row);
    int end = offs[row];
    const uint4* hp = (const uint4*)Hin16;
    float4 a = make_float4(0.f, 0.f, 0.f, 0.f);
    float4 b = make_float4(0.f, 0.f, 0.f, 0.f);
    for (int i = beg + sub; i < end; i += 4) {
        int2 e = edata2[i];
        int t = (e.x >> 17) & 3;
        uint4 h = hp[(size_t)(e.x & 0x1FFFF) * 16 + s16];
        unsigned wp = (unsigned)e.y;
        float w0 = bflo(wp) * r0[t], w1 = bfhi(wp) * r1[t];
        a.x = fmaf(w0, bflo(h.x), a.x);
        a.y = fmaf(w1, bfhi(h.x), a.y);
        a.z = fmaf(w0, bflo(h.y), a.z);
        a.w = fmaf(w1, bfhi(h.y), a.w);
        b.x = fmaf(w0, bflo(h.z), b.x);
        b.y = fmaf(w1, bfhi(h.z), b.y);
        b.z = fmaf(w0, bflo(h.w), b.z);
        b.w = fmaf(w1, bfhi(h.w), b.w);
    }
    qreduce(a, b);

    if (sub == 0) {
        uint4 xu = ((const uint4*)Xp16)[(size_t)row * 16 + s16];
        int d0 = 4 * s16;
        hc[w][d0 + 0]      = fmaxf(BETA * bflo(xu.x) + (1.f - BETA) * a.x, 0.f);
        hc[w][DD + d0 + 0] = fmaxf(BETA * bfhi(xu.x) + (1.f - BETA) * a.y, 0.f);
        hc[w][d0 + 1]      = fmaxf(BETA * bflo(xu.y) + (1.f - BETA) * a.z, 0.f);
        hc[w][DD + d0 + 1] = fmaxf(BETA * bfhi(xu.y) + (1.f - BETA) * a.w, 0.f);
        hc[w][d0 + 2]      = fmaxf(BETA * bflo(xu.z) + (1.f - BETA) * b.x, 0.f);
        hc[w][DD + d0 + 2] = fmaxf(BETA * bfhi(xu.z) + (1.f - BETA) * b.y, 0.f);
        hc[w][d0 + 3]      = fmaxf(BETA * bflo(xu.w) + (1.f - BETA) * b.z, 0.f);
        hc[w][DD + d0 + 3] = fmaxf(BETA * bfhi(xu.w) + (1.f - BETA) * b.w, 0.f);
    }
    __syncthreads();

    float a1 = l1b[lane];
    #pragma unroll 8
    for (int k = 0; k < W_INF; ++k)
        a1 = fmaf(hc[w][k], l1w[k * DD + lane], a1);
    hmid[w][lane] = a1;
    __syncthreads();

    if (lane < NUM_CLASS) {
        float o = lb[lane];
        #pragma unroll 8
        for (int k = 0; k < DD; ++k)
            o = fmaf(hmid[w][k], lw[k * NUM_CLASS + lane], o);
        out[(size_t)m * NUM_CLASS + lane] = o;
    }
}

// ---------------------------------------------------------------------------
extern "C" void kernel_launch(void* const* d_in, const int* in_sizes, int n_in,
                              void* d_out, int out_size, void* d_ws, size_t ws_size,
                              hipStream_t stream) {
    const float* X            = (const float*)d_in[0];
    const float* edge_value   = (const float*)d_in[1];
    const float* conv_weights = (const float*)d_in[2];
    const float* Ws           = (const float*)d_in[3];
    const float* lin1_w       = (const float*)d_in[4];
    const float* lin1_b       = (const float*)d_in[5];
    const float* lin_w        = (const float*)d_in[6];
    const float* lin_b        = (const float*)d_in[7];
    const int*   edge_index   = (const int*)d_in[8];
    const int*   target_x     = (const int*)d_in[9];
    float* out = (float*)d_out;

    unsigned*       Xp16 = (unsigned*)d_ws;                   // 25.6 MB
    unsigned*       H116 = Xp16 + PLANE2;                     // 25.6 MB
    unsigned short* Wsb  = (unsigned short*)(H116 + PLANE2);  // 32 KB
    int*            offs = (int*)(Wsb + C_CH * W_INF * DD);   // N ints
    int*            cursor = offs + N_NODES;                  // 512
    int2*           edata2 = (int2*)(cursor + 512);           // NBKT*BPAD int2 (15.2 MB)

    prep_kernel<<<66, 256, 0, stream>>>(Ws, Wsb, cursor);
    build_proj_kernel<<<NPART_BLK + PROJ_BLK, 256, 0, stream>>>(
        edge_index, edge_value, conv_weights, cursor, edata2, X, Wsb, Xp16);
    rowsort_kernel<<<NBKT, 512, 0, stream>>>(cursor, edata2, offs);
    spmm_gather<<<(N_NODES * 64) / 256, 256, 0, stream>>>(Xp16, H116, offs, edata2);
    tgt_tail_kernel<<<M_TGT / 4, 256, 0, stream>>>(H116, Xp16, offs, edata2,
                                                   conv_weights, target_x,
                                                   lin1_w, lin1_b, lin_w, lin_b, out);
}